// Round 1
// baseline (425.638 us; speedup 1.0000x reference)
//
#include <hip/hip_runtime.h>

// InterpretableMultiHeadAttention: B=8,S=1024,H=1024,NH=16,D=64,V=1024
// out = (mean_n softmax(causal(qh_n kh_n^T / 8))) @ (v Wv + bv)
// Pipeline: f16 convert -> 3 proj GEMMs (MFMA 16x16x32_f16) -> stats (m,1/l)
//           -> pbar accumulation (heads looped in-block, LDS fp32 tile) -> PV GEMM.
// ws usage ~119 MB.

#define NHEAD 16
#define BATCH 8
#define SEQ   1024
#define HID   1024
#define DHEAD 64

typedef _Float16 f16;
typedef _Float16 f16x4 __attribute__((ext_vector_type(4)));
typedef _Float16 f16x8 __attribute__((ext_vector_type(8)));
typedef float    f32x4 __attribute__((ext_vector_type(4)));

__device__ __forceinline__ f32x4 mfma16(f16x8 a, f16x8 b, f32x4 c) {
  return __builtin_amdgcn_mfma_f32_16x16x32_f16(a, b, c, 0, 0, 0);
}

// ---------------- conversions ----------------

__global__ __launch_bounds__(256) void conv_f16(const float* __restrict__ src,
                                                f16* __restrict__ dst, int n) {
  int i = (blockIdx.x * 256 + threadIdx.x) * 4;
  if (i >= n) return;
  float4 f = *(const float4*)(src + i);
  f16x4 o = { (f16)f.x, (f16)f.y, (f16)f.z, (f16)f.w };
  *(f16x4*)(dst + i) = o;
}

// in[n][h][d] -> out[n][d][h]  (Wv: n=1, h=1024, d=V=1024)
__global__ __launch_bounds__(256) void conv_w(const float* __restrict__ src,
                                              f16* __restrict__ dst,
                                              int NHp, int Hp, int Dp) {
  int idx = blockIdx.x * 256 + threadIdx.x;
  int total = NHp * Hp * Dp;
  if (idx >= total) return;
  int d = idx % Dp;
  int h = (idx / Dp) % Hp;
  int nn = idx / (Dp * Hp);
  dst[((size_t)nn * Dp + d) * Hp + h] = (f16)src[idx];
}

// ---------------- GEMM: C[m][j] = sum_k A[m][k] * Bt[j][k] (+bias) ----------------
// 128x128 tile, BK=64, 4 waves (2x2), each wave 64x64 via 4x4 16x16 frags.
// epi 0: QH/KH scatter [(j>>6)][m>>10][m&1023][j&63] f16, bias[j]
// epi 1: vvT [j>>10][m][j&1023] f16, bias[m]
// epi 2: fp32 out, batched via sCb

__global__ __launch_bounds__(256) void gemm_bt(
    const f16* __restrict__ A, const f16* __restrict__ Bt,
    const float* __restrict__ bias, void* __restrict__ C,
    int M, int N, int K, long sAb, long sBb, long sCb, int epi) {
  A  += (size_t)blockIdx.z * sAb;
  Bt += (size_t)blockIdx.z * sBb;

  __shared__ alignas(16) f16 la[128 * 64];
  __shared__ alignas(16) f16 lb[128 * 64];

  const int tid = threadIdx.x;
  const int lane = tid & 63;
  const int wave = tid >> 6;
  const int wr = wave >> 1, wc = wave & 1;
  const int row0 = blockIdx.x * 128, col0 = blockIdx.y * 128;

  f32x4 acc[4][4];
#pragma unroll
  for (int i = 0; i < 4; i++)
#pragma unroll
    for (int j = 0; j < 4; j++) acc[i][j] = (f32x4){0.f, 0.f, 0.f, 0.f};

  for (int k0 = 0; k0 < K; k0 += 64) {
#pragma unroll
    for (int i = 0; i < 4; i++) {
      int c = tid + i * 256;          // 0..1023 chunk id
      int r = c >> 3, cc = c & 7;     // row, 16B chunk within row
      *(int4*)&la[r * 64 + cc * 8] =
          *(const int4*)&A[(size_t)(row0 + r) * K + k0 + cc * 8];
      *(int4*)&lb[r * 64 + cc * 8] =
          *(const int4*)&Bt[(size_t)(col0 + r) * K + k0 + cc * 8];
    }
    __syncthreads();
#pragma unroll
    for (int ks = 0; ks < 2; ks++) {
      f16x8 af[4], bfr[4];
#pragma unroll
      for (int mi = 0; mi < 4; mi++)
        af[mi] = *(const f16x8*)&la[(wr * 64 + mi * 16 + (lane & 15)) * 64 +
                                    ks * 32 + (lane >> 4) * 8];
#pragma unroll
      for (int ni = 0; ni < 4; ni++)
        bfr[ni] = *(const f16x8*)&lb[(wc * 64 + ni * 16 + (lane & 15)) * 64 +
                                     ks * 32 + (lane >> 4) * 8];
#pragma unroll
      for (int mi = 0; mi < 4; mi++)
#pragma unroll
        for (int ni = 0; ni < 4; ni++)
          acc[mi][ni] = mfma16(af[mi], bfr[ni], acc[mi][ni]);
    }
    __syncthreads();
  }

#pragma unroll
  for (int mi = 0; mi < 4; mi++) {
#pragma unroll
    for (int ni = 0; ni < 4; ni++) {
#pragma unroll
      for (int r = 0; r < 4; r++) {
        int m = row0 + wr * 64 + mi * 16 + ((lane >> 4) << 2) + r;
        int j = col0 + wc * 64 + ni * 16 + (lane & 15);
        float val = acc[mi][ni][r];
        if (epi == 0) {
          val += bias[j];
          int bb = m >> 10, s = m & 1023, hn = j >> 6, d = j & 63;
          ((f16*)C)[(((size_t)hn * BATCH + bb) * SEQ + s) * DHEAD + d] = (f16)val;
        } else if (epi == 1) {
          val += bias[m];
          int bb = j >> 10, t = j & 1023;
          ((f16*)C)[((size_t)bb * SEQ + m) * SEQ + t] = (f16)val;
        } else {
          ((float*)C)[(size_t)blockIdx.z * sCb + (size_t)m * N + j] = val;
        }
      }
    }
  }
}

// ---------------- attention pass 1: per-row max (m) and 1/sum (rl), exp2 domain ----------------
// grid (sb=16, b=8, n=16), block 256 (4 waves x 16 rows)

__global__ __launch_bounds__(256) void attn_stats(
    const f16* __restrict__ QH, const f16* __restrict__ KH,
    float* __restrict__ m_ws, float* __restrict__ rl_ws) {
  const int sb = blockIdx.x, b = blockIdx.y, n = blockIdx.z;
  const int s0 = sb * 64;
  const f16* qh = QH + ((size_t)n * BATCH + b) * SEQ * DHEAD;
  const f16* kh = KH + ((size_t)n * BATCH + b) * SEQ * DHEAD;

  __shared__ alignas(16) f16 lq[64 * 64];
  __shared__ alignas(16) f16 lk[64 * 64];

  const int tid = threadIdx.x, lane = tid & 63, wave = tid >> 6;

  for (int i = tid; i < 512; i += 256)
    *(int4*)&lq[i * 8] = *(const int4*)&qh[(size_t)s0 * 64 + i * 8];
  __syncthreads();

  f16x8 aq0 = *(const f16x8*)&lq[(wave * 16 + (lane & 15)) * 64 + (lane >> 4) * 8];
  f16x8 aq1 = *(const f16x8*)&lq[(wave * 16 + (lane & 15)) * 64 + 32 + (lane >> 4) * 8];

  const float sl2e = 0.125f * 1.44269504088896f;  // scale * log2(e)
  float m_run[4] = {-__builtin_inff(), -__builtin_inff(), -__builtin_inff(), -__builtin_inff()};
  float l_run[4] = {0.f, 0.f, 0.f, 0.f};
  const int srow = s0 + wave * 16 + ((lane >> 4) << 2);

  for (int tt = 0; tt <= sb; tt++) {
    __syncthreads();  // previous iter's lk reads complete
    for (int i = tid; i < 512; i += 256)
      *(int4*)&lk[i * 8] = *(const int4*)&kh[(size_t)tt * 4096 + i * 8];
    __syncthreads();

    f32x4 sc[4];
#pragma unroll
    for (int tc = 0; tc < 4; tc++) {
      f16x8 b0 = *(const f16x8*)&lk[(tc * 16 + (lane & 15)) * 64 + (lane >> 4) * 8];
      f16x8 b1 = *(const f16x8*)&lk[(tc * 16 + (lane & 15)) * 64 + 32 + (lane >> 4) * 8];
      f32x4 c = (f32x4){0.f, 0.f, 0.f, 0.f};
      c = mfma16(aq0, b0, c);
      c = mfma16(aq1, b1, c);
      sc[tc] = c;
    }

#pragma unroll
    for (int r = 0; r < 4; r++) {
      int sg = srow + r;
      float e[4];
      float mt = -__builtin_inff();
#pragma unroll
      for (int tc = 0; tc < 4; tc++) {
        int tg = tt * 64 + tc * 16 + (lane & 15);
        e[tc] = (tg <= sg) ? sc[tc][r] * sl2e : -__builtin_inff();
        mt = fmaxf(mt, e[tc]);
      }
#pragma unroll
      for (int off = 1; off < 16; off <<= 1) mt = fmaxf(mt, __shfl_xor(mt, off));
      float mnew = fmaxf(m_run[r], mt);
      float lt = 0.f;
#pragma unroll
      for (int tc = 0; tc < 4; tc++) lt += exp2f(e[tc] - mnew);
#pragma unroll
      for (int off = 1; off < 16; off <<= 1) lt += __shfl_xor(lt, off);
      l_run[r] = l_run[r] * exp2f(m_run[r] - mnew) + lt;
      m_run[r] = mnew;
    }
  }

  if ((lane & 15) == 0) {
    size_t base = ((size_t)n * BATCH + b) * SEQ;
#pragma unroll
    for (int r = 0; r < 4; r++) {
      m_ws[base + srow + r] = m_run[r];
      rl_ws[base + srow + r] = 1.0f / l_run[r];
    }
  }
}

// ---------------- attention pass 2: pbar = mean_n p_n, f16 ----------------
// grid (tchunk=8, sb=16, b=8), block 256. Heads looped inside; LDS fp32 tile.

__global__ __launch_bounds__(256) void attn_pbar(
    const f16* __restrict__ QH, const f16* __restrict__ KH,
    const float* __restrict__ m_ws, const float* __restrict__ rl_ws,
    f16* __restrict__ pbar) {
  const int t0 = blockIdx.x * 128;
  const int s0 = blockIdx.y * 64;
  const int b = blockIdx.z;
  const int tid = threadIdx.x, lane = tid & 63, wave = tid >> 6;

  if (t0 > s0 + 63) {  // fully masked tile
    for (int i = tid; i < 64 * 128; i += 256) {
      int r = i >> 7, c = i & 127;
      pbar[((size_t)b * SEQ + s0 + r) * SEQ + t0 + c] = (f16)0.f;
    }
    return;
  }

  __shared__ alignas(16) f16 lq[64 * 64];
  __shared__ alignas(16) f16 lk[128 * 64];
  __shared__ float pb[64][132];  // +4 pad -> 2-way LDS RMW (free)

  for (int i = tid; i < 64 * 132; i += 256) ((float*)pb)[i] = 0.f;

  const float sl2e = 0.125f * 1.44269504088896f;
  const int rloc = wave * 16 + ((lane >> 4) << 2);
  const int srow = s0 + rloc;

  for (int n = 0; n < NHEAD; n++) {
    __syncthreads();  // pb zero-init visible; previous head's lq/lk reads done
    const f16* qh = QH + ((size_t)n * BATCH + b) * SEQ * DHEAD;
    const f16* kh = KH + ((size_t)n * BATCH + b) * SEQ * DHEAD;
    for (int i = tid; i < 512; i += 256)
      *(int4*)&lq[i * 8] = *(const int4*)&qh[(size_t)s0 * 64 + i * 8];
    for (int i = tid; i < 1024; i += 256)
      *(int4*)&lk[i * 8] = *(const int4*)&kh[(size_t)t0 * 64 + i * 8];
    __syncthreads();

    f16x8 aq0 = *(const f16x8*)&lq[(wave * 16 + (lane & 15)) * 64 + (lane >> 4) * 8];
    f16x8 aq1 = *(const f16x8*)&lq[(wave * 16 + (lane & 15)) * 64 + 32 + (lane >> 4) * 8];

    float mrow[4], rlrow[4];
    size_t mlbase = ((size_t)n * BATCH + b) * SEQ + srow;
#pragma unroll
    for (int r = 0; r < 4; r++) {
      mrow[r] = m_ws[mlbase + r];
      rlrow[r] = rl_ws[mlbase + r] * (1.0f / 16.0f);
    }

#pragma unroll
    for (int tc = 0; tc < 8; tc++) {
      f16x8 b0 = *(const f16x8*)&lk[(tc * 16 + (lane & 15)) * 64 + (lane >> 4) * 8];
      f16x8 b1 = *(const f16x8*)&lk[(tc * 16 + (lane & 15)) * 64 + 32 + (lane >> 4) * 8];
      f32x4 c = (f32x4){0.f, 0.f, 0.f, 0.f};
      c = mfma16(aq0, b0, c);
      c = mfma16(aq1, b1, c);
      int tg = t0 + tc * 16 + (lane & 15);
#pragma unroll
      for (int r = 0; r < 4; r++) {
        int sg = srow + r;
        float p = (tg <= sg) ? exp2f(c[r] * sl2e - mrow[r]) * rlrow[r] : 0.f;
        pb[rloc + r][tc * 16 + (lane & 15)] += p;
      }
    }
  }
  __syncthreads();
  for (int i = tid; i < 64 * 128; i += 256) {
    int r = i >> 7, c = i & 127;
    pbar[((size_t)b * SEQ + s0 + r) * SEQ + t0 + c] = (f16)pb[r][c];
  }
}

// ---------------- launcher ----------------

extern "C" void kernel_launch(void* const* d_in, const int* in_sizes, int n_in,
                              void* d_out, int out_size, void* d_ws, size_t ws_size,
                              hipStream_t stream) {
  (void)in_sizes; (void)n_in; (void)out_size; (void)ws_size;
  const float* q  = (const float*)d_in[0];
  const float* k  = (const float*)d_in[1];
  const float* v  = (const float*)d_in[2];
  const float* Wq = (const float*)d_in[3];
  const float* bq = (const float*)d_in[4];
  const float* Wk = (const float*)d_in[5];
  const float* bk = (const float*)d_in[6];
  const float* Wv = (const float*)d_in[7];
  const float* bv = (const float*)d_in[8];
  float* out = (float*)d_out;

  const size_t EL  = (size_t)BATCH * SEQ * HID;      // 8388608
  const size_t WEL = (size_t)NHEAD * HID * DHEAD;    // 1048576

  char* ws = (char*)d_ws;
  f16* qbf = (f16*)ws;  ws += EL * 2;
  f16* kbf = (f16*)ws;  ws += EL * 2;
  f16* vbf = (f16*)ws;  ws += EL * 2;
  f16* WqT = (f16*)ws;  ws += WEL * 2;
  f16* WkT = (f16*)ws;  ws += WEL * 2;
  f16* WvT = (f16*)ws;  ws += WEL * 2;
  f16* QHb = (f16*)ws;  ws += EL * 2;   // [n][b][s][d]
  f16* KHb = (f16*)ws;  ws += EL * 2;   // [n][b][t][d]
  f16* vvT = (f16*)ws;  ws += EL * 2;   // [b][v][t]
  float* m_ws  = (float*)ws; ws += (size_t)NHEAD * BATCH * SEQ * 4;
  float* rl_ws = (float*)ws; ws += (size_t)NHEAD * BATCH * SEQ * 4;
  f16* pbar = (f16*)ws; ws += EL * 2;   // [b][s][t]

  conv_f16<<<EL / 4 / 256, 256, 0, stream>>>(q, qbf, (int)EL);
  conv_f16<<<EL / 4 / 256, 256, 0, stream>>>(k, kbf, (int)EL);
  conv_f16<<<EL / 4 / 256, 256, 0, stream>>>(v, vbf, (int)EL);
  conv_w<<<WEL / 256, 256, 0, stream>>>(Wq, WqT, NHEAD, HID, DHEAD);
  conv_w<<<WEL / 256, 256, 0, stream>>>(Wk, WkT, NHEAD, HID, DHEAD);
  conv_w<<<WEL / 256, 256, 0, stream>>>(Wv, WvT, 1, HID, SEQ);

  // QH = q @ Wq' (+bq), scatter to [n][b][s][d]
  gemm_bt<<<dim3(64, 8, 1), 256, 0, stream>>>(qbf, WqT, bq, QHb,
                                              8192, 1024, 1024, 0, 0, 0, 0);
  gemm_bt<<<dim3(64, 8, 1), 256, 0, stream>>>(kbf, WkT, bk, KHb,
                                              8192, 1024, 1024, 0, 0, 0, 0);
  // vvT[b][v][t] = WvT (1024x1024) x v^T, bias bv[row]
  gemm_bt<<<dim3(8, 64, 1), 256, 0, stream>>>(WvT, vbf, bv, vvT,
                                              1024, 8192, 1024, 0, 0, 0, 1);

  attn_stats<<<dim3(16, 8, 16), 256, 0, stream>>>(QHb, KHb, m_ws, rl_ws);
  attn_pbar<<<dim3(8, 16, 8), 256, 0, stream>>>(QHb, KHb, m_ws, rl_ws, pbar);

  // out[b] = pbar[b] @ vv[b]  (A=pbar, Bt=vvT), fp32 out
  gemm_bt<<<dim3(8, 8, 8), 256, 0, stream>>>(pbar, vvT, nullptr, out,
                                             1024, 1024, 1024,
                                             1048576, 1048576, 1048576, 2);
}

// Round 2
// 334.049 us; speedup vs baseline: 1.2742x; 1.2742x over previous
//
#include <hip/hip_runtime.h>

// InterpretableMultiHeadAttention: B=8,S=1024,H=1024,NH=16,D=64,V=1024
// out = (mean_n softmax(causal(qh_n kh_n^T / 8))) @ (v Wv + bv)
// Round 2: global_load_lds(16B) staging everywhere (pre-swizzled source,
// XOR-swizzled reads), register pbar accumulation, causal K-limit in PV.

#define NHEAD 16
#define BATCH 8
#define SEQ   1024
#define HID   1024
#define DHEAD 64

typedef _Float16 f16;
typedef _Float16 f16x4 __attribute__((ext_vector_type(4)));
typedef _Float16 f16x8 __attribute__((ext_vector_type(8)));
typedef float    f32x4 __attribute__((ext_vector_type(4)));

__device__ __forceinline__ f32x4 mfma16(f16x8 a, f16x8 b, f32x4 c) {
  return __builtin_amdgcn_mfma_f32_16x16x32_f16(a, b, c, 0, 0, 0);
}

__device__ __forceinline__ void gload16(const f16* g, f16* l) {
  __builtin_amdgcn_global_load_lds(
      (const __attribute__((address_space(1))) void*)g,
      (__attribute__((address_space(3))) void*)l, 16, 0, 0);
}

// Stage nch 16B-chunks (nch multiple of 256) of a [rows][64]-f16 tile from g
// (row stride ldg f16) into lds. LDS layout is linear; the global SOURCE chunk
// is pre-swizzled (c16 ^ (row&7)) so reads use the same XOR and hit the
// 8-cycle bank floor instead of 16.
__device__ __forceinline__ void stage_swz(const f16* __restrict__ g, int ldg,
                                          f16* lds, int nch, int tid) {
  for (int idx = tid; idx < nch; idx += 256) {
    int row = idx >> 3, c16 = idx & 7;
    int sc = c16 ^ (row & 7);
    gload16(g + (size_t)row * ldg + sc * 8, lds + (size_t)(idx & ~63) * 8);
  }
}

// Read one f16x8 fragment at (row, 16B-chunk c16) with the matching XOR.
__device__ __forceinline__ f16x8 lds_frag(const f16* lds, int row, int c16) {
  int sc = c16 ^ (row & 7);
  return *(const f16x8*)&lds[row * 64 + sc * 8];
}

// ---------------- conversions ----------------

__global__ __launch_bounds__(256) void conv_f16(const float* __restrict__ src,
                                                f16* __restrict__ dst, int n) {
  int i = (blockIdx.x * 256 + threadIdx.x) * 4;
  if (i >= n) return;
  float4 f = *(const float4*)(src + i);
  f16x4 o = { (f16)f.x, (f16)f.y, (f16)f.z, (f16)f.w };
  *(f16x4*)(dst + i) = o;
}

// in[n][h][d] -> out[n][d][h]  (Wv: n=1, h=1024, d=V=1024)
__global__ __launch_bounds__(256) void conv_w(const float* __restrict__ src,
                                              f16* __restrict__ dst,
                                              int NHp, int Hp, int Dp) {
  int idx = blockIdx.x * 256 + threadIdx.x;
  int total = NHp * Hp * Dp;
  if (idx >= total) return;
  int d = idx % Dp;
  int h = (idx / Dp) % Hp;
  int nn = idx / (Dp * Hp);
  dst[((size_t)nn * Dp + d) * Hp + h] = (f16)src[idx];
}

// ---------------- GEMM: C[m][j] = sum_k A[m][k] * Bt[j][k] (+bias) ----------------
// 128x128 tile, BK=64, 4 waves (2x2), each wave 64x64 via 4x4 16x16 frags.
// epi 0: QH/KH scatter [(j>>6)][m>>10][m&1023][j&63] f16, bias[j]
// epi 1: vvT [j>>10][m][j&1023] f16, bias[m]
// epi 2: fp32 out, batched via sCb
// causal=1: Kend = min(K, row0+128)  (A is lower-triangular pbar)

__global__ __launch_bounds__(256) void gemm_bt(
    const f16* __restrict__ A, const f16* __restrict__ Bt,
    const float* __restrict__ bias, void* __restrict__ C,
    int M, int N, int K, long sAb, long sBb, long sCb, int epi, int causal) {
  A  += (size_t)blockIdx.z * sAb;
  Bt += (size_t)blockIdx.z * sBb;

  __shared__ alignas(16) f16 la[128 * 64];
  __shared__ alignas(16) f16 lb[128 * 64];

  const int tid = threadIdx.x;
  const int lane = tid & 63;
  const int wave = tid >> 6;
  const int wr = wave >> 1, wc = wave & 1;
  const int row0 = blockIdx.x * 128, col0 = blockIdx.y * 128;
  const int Kend = causal ? ((row0 + 128 < K) ? row0 + 128 : K) : K;

  f32x4 acc[4][4];
#pragma unroll
  for (int i = 0; i < 4; i++)
#pragma unroll
    for (int j = 0; j < 4; j++) acc[i][j] = (f32x4){0.f, 0.f, 0.f, 0.f};

  for (int k0 = 0; k0 < Kend; k0 += 64) {
    __syncthreads();  // protect previous iteration's LDS reads
    stage_swz(A + (size_t)row0 * K + k0, K, la, 1024, tid);
    stage_swz(Bt + (size_t)col0 * K + k0, K, lb, 1024, tid);
    __syncthreads();  // barrier drains vmcnt -> loads landed
#pragma unroll
    for (int ks = 0; ks < 2; ks++) {
      f16x8 af[4], bfr[4];
#pragma unroll
      for (int mi = 0; mi < 4; mi++)
        af[mi] = lds_frag(la, wr * 64 + mi * 16 + (lane & 15), ks * 4 + (lane >> 4));
#pragma unroll
      for (int ni = 0; ni < 4; ni++)
        bfr[ni] = lds_frag(lb, wc * 64 + ni * 16 + (lane & 15), ks * 4 + (lane >> 4));
#pragma unroll
      for (int mi = 0; mi < 4; mi++)
#pragma unroll
        for (int ni = 0; ni < 4; ni++)
          acc[mi][ni] = mfma16(af[mi], bfr[ni], acc[mi][ni]);
    }
  }

#pragma unroll
  for (int mi = 0; mi < 4; mi++) {
#pragma unroll
    for (int ni = 0; ni < 4; ni++) {
#pragma unroll
      for (int r = 0; r < 4; r++) {
        int m = row0 + wr * 64 + mi * 16 + ((lane >> 4) << 2) + r;
        int j = col0 + wc * 64 + ni * 16 + (lane & 15);
        float val = acc[mi][ni][r];
        if (epi == 0) {
          val += bias[j];
          int bb = m >> 10, s = m & 1023, hn = j >> 6, d = j & 63;
          ((f16*)C)[(((size_t)hn * BATCH + bb) * SEQ + s) * DHEAD + d] = (f16)val;
        } else if (epi == 1) {
          val += bias[m];
          int bb = j >> 10, t = j & 1023;
          ((f16*)C)[((size_t)bb * SEQ + m) * SEQ + t] = (f16)val;
        } else {
          ((float*)C)[(size_t)blockIdx.z * sCb + (size_t)m * N + j] = val;
        }
      }
    }
  }
}

// ---------------- attention pass 1: per-row max (m) and 1/sum (rl), exp2 domain ----------------
// grid (sb=16, b=8, n=16), block 256 (4 waves x 16 rows)

__global__ __launch_bounds__(256) void attn_stats(
    const f16* __restrict__ QH, const f16* __restrict__ KH,
    float* __restrict__ m_ws, float* __restrict__ rl_ws) {
  const int sb = blockIdx.x, b = blockIdx.y, n = blockIdx.z;
  const int s0 = sb * 64;
  const f16* qh = QH + ((size_t)n * BATCH + b) * SEQ * DHEAD;
  const f16* kh = KH + ((size_t)n * BATCH + b) * SEQ * DHEAD;

  __shared__ alignas(16) f16 lq[64 * 64];
  __shared__ alignas(16) f16 lk[64 * 64];

  const int tid = threadIdx.x, lane = tid & 63, wave = tid >> 6;

  stage_swz(qh + (size_t)s0 * 64, 64, lq, 512, tid);
  __syncthreads();

  f16x8 aq0 = lds_frag(lq, wave * 16 + (lane & 15), (lane >> 4));
  f16x8 aq1 = lds_frag(lq, wave * 16 + (lane & 15), 4 + (lane >> 4));

  const float sl2e = 0.125f * 1.44269504088896f;  // scale * log2(e)
  float m_run[4] = {-__builtin_inff(), -__builtin_inff(), -__builtin_inff(), -__builtin_inff()};
  float l_run[4] = {0.f, 0.f, 0.f, 0.f};
  const int srow = s0 + wave * 16 + ((lane >> 4) << 2);

  for (int tt = 0; tt <= sb; tt++) {
    __syncthreads();  // previous iter's lk reads complete
    stage_swz(kh + (size_t)tt * 4096, 64, lk, 512, tid);
    __syncthreads();

    f32x4 sc[4];
#pragma unroll
    for (int tc = 0; tc < 4; tc++) {
      f16x8 b0 = lds_frag(lk, tc * 16 + (lane & 15), (lane >> 4));
      f16x8 b1 = lds_frag(lk, tc * 16 + (lane & 15), 4 + (lane >> 4));
      f32x4 c = (f32x4){0.f, 0.f, 0.f, 0.f};
      c = mfma16(aq0, b0, c);
      c = mfma16(aq1, b1, c);
      sc[tc] = c;
    }

#pragma unroll
    for (int r = 0; r < 4; r++) {
      int sg = srow + r;
      float e[4];
      float mt = -__builtin_inff();
#pragma unroll
      for (int tc = 0; tc < 4; tc++) {
        int tg = tt * 64 + tc * 16 + (lane & 15);
        e[tc] = (tg <= sg) ? sc[tc][r] * sl2e : -__builtin_inff();
        mt = fmaxf(mt, e[tc]);
      }
#pragma unroll
      for (int off = 1; off < 16; off <<= 1) mt = fmaxf(mt, __shfl_xor(mt, off));
      float mnew = fmaxf(m_run[r], mt);
      float lt = 0.f;
#pragma unroll
      for (int tc = 0; tc < 4; tc++) lt += exp2f(e[tc] - mnew);
#pragma unroll
      for (int off = 1; off < 16; off <<= 1) lt += __shfl_xor(lt, off);
      l_run[r] = l_run[r] * exp2f(m_run[r] - mnew) + lt;
      m_run[r] = mnew;
    }
  }

  if ((lane & 15) == 0) {
    size_t base = ((size_t)n * BATCH + b) * SEQ;
#pragma unroll
    for (int r = 0; r < 4; r++) {
      m_ws[base + srow + r] = m_run[r];
      rl_ws[base + srow + r] = 1.0f / l_run[r];
    }
  }
}

// ---------------- attention pass 2: pbar = mean_n p_n, f16, register accumulation ----------------
// grid (tchunk=8, sb=16, b=8), block 256. Heads looped inside; pacc[8][4] in VGPRs.
// Fully-masked tiles return without writing: PV's causal K-limit never reads them.

__global__ __launch_bounds__(256) void attn_pbar(
    const f16* __restrict__ QH, const f16* __restrict__ KH,
    const float* __restrict__ m_ws, const float* __restrict__ rl_ws,
    f16* __restrict__ pbar) {
  const int t0 = blockIdx.x * 128;
  const int s0 = blockIdx.y * 64;
  const int b = blockIdx.z;
  if (t0 > s0 + 63) return;  // fully masked; PV never reads this region

  __shared__ alignas(16) f16 lq[64 * 64];
  __shared__ alignas(16) f16 lk[128 * 64];

  const int tid = threadIdx.x, lane = tid & 63, wave = tid >> 6;
  const float sl2e = 0.125f * 1.44269504088896f;
  const int rloc = wave * 16 + ((lane >> 4) << 2);
  const int srow = s0 + rloc;

  float pacc[8][4];
#pragma unroll
  for (int tc = 0; tc < 8; tc++)
#pragma unroll
    for (int r = 0; r < 4; r++) pacc[tc][r] = 0.f;

  for (int n = 0; n < NHEAD; n++) {
    const f16* qh = QH + ((size_t)n * BATCH + b) * SEQ * DHEAD;
    const f16* kh = KH + ((size_t)n * BATCH + b) * SEQ * DHEAD;
    __syncthreads();  // previous head's LDS reads complete
    stage_swz(qh + (size_t)s0 * 64, 64, lq, 512, tid);
    stage_swz(kh + (size_t)t0 * 64, 64, lk, 1024, tid);
    __syncthreads();  // loads landed

    f16x8 aq0 = lds_frag(lq, wave * 16 + (lane & 15), (lane >> 4));
    f16x8 aq1 = lds_frag(lq, wave * 16 + (lane & 15), 4 + (lane >> 4));

    size_t mlbase = ((size_t)n * BATCH + b) * SEQ + srow;
    float4 mr = *(const float4*)&m_ws[mlbase];
    float4 rl = *(const float4*)&rl_ws[mlbase];
    float mrow[4] = {mr.x, mr.y, mr.z, mr.w};
    float rlrow[4] = {rl.x * (1.f / 16.f), rl.y * (1.f / 16.f),
                      rl.z * (1.f / 16.f), rl.w * (1.f / 16.f)};

#pragma unroll
    for (int tc = 0; tc < 8; tc++) {
      f16x8 b0 = lds_frag(lk, tc * 16 + (lane & 15), (lane >> 4));
      f16x8 b1 = lds_frag(lk, tc * 16 + (lane & 15), 4 + (lane >> 4));
      f32x4 c = (f32x4){0.f, 0.f, 0.f, 0.f};
      c = mfma16(aq0, b0, c);
      c = mfma16(aq1, b1, c);
      int tg = t0 + tc * 16 + (lane & 15);
#pragma unroll
      for (int r = 0; r < 4; r++) {
        if (tg <= srow + r)
          pacc[tc][r] += exp2f(c[r] * sl2e - mrow[r]) * rlrow[r];
      }
    }
  }

#pragma unroll
  for (int tc = 0; tc < 8; tc++) {
    int tg = t0 + tc * 16 + (lane & 15);
#pragma unroll
    for (int r = 0; r < 4; r++)
      pbar[((size_t)b * SEQ + srow + r) * SEQ + tg] = (f16)pacc[tc][r];
  }
}

// ---------------- launcher ----------------

extern "C" void kernel_launch(void* const* d_in, const int* in_sizes, int n_in,
                              void* d_out, int out_size, void* d_ws, size_t ws_size,
                              hipStream_t stream) {
  (void)in_sizes; (void)n_in; (void)out_size; (void)ws_size;
  const float* q  = (const float*)d_in[0];
  const float* k  = (const float*)d_in[1];
  const float* v  = (const float*)d_in[2];
  const float* Wq = (const float*)d_in[3];
  const float* bq = (const float*)d_in[4];
  const float* Wk = (const float*)d_in[5];
  const float* bk = (const float*)d_in[6];
  const float* Wv = (const float*)d_in[7];
  const float* bv = (const float*)d_in[8];
  float* out = (float*)d_out;

  const size_t EL  = (size_t)BATCH * SEQ * HID;      // 8388608
  const size_t WEL = (size_t)NHEAD * HID * DHEAD;    // 1048576

  char* ws = (char*)d_ws;
  f16* qbf = (f16*)ws;  ws += EL * 2;
  f16* kbf = (f16*)ws;  ws += EL * 2;
  f16* vbf = (f16*)ws;  ws += EL * 2;
  f16* WqT = (f16*)ws;  ws += WEL * 2;
  f16* WkT = (f16*)ws;  ws += WEL * 2;
  f16* WvT = (f16*)ws;  ws += WEL * 2;
  f16* QHb = (f16*)ws;  ws += EL * 2;   // [n][b][s][d]
  f16* KHb = (f16*)ws;  ws += EL * 2;   // [n][b][t][d]
  f16* vvT = (f16*)ws;  ws += EL * 2;   // [b][v][t]
  float* m_ws  = (float*)ws; ws += (size_t)NHEAD * BATCH * SEQ * 4;
  float* rl_ws = (float*)ws; ws += (size_t)NHEAD * BATCH * SEQ * 4;
  f16* pbar = (f16*)ws; ws += EL * 2;   // [b][s][t]

  conv_f16<<<EL / 4 / 256, 256, 0, stream>>>(q, qbf, (int)EL);
  conv_f16<<<EL / 4 / 256, 256, 0, stream>>>(k, kbf, (int)EL);
  conv_f16<<<EL / 4 / 256, 256, 0, stream>>>(v, vbf, (int)EL);
  conv_w<<<WEL / 256, 256, 0, stream>>>(Wq, WqT, NHEAD, HID, DHEAD);
  conv_w<<<WEL / 256, 256, 0, stream>>>(Wk, WkT, NHEAD, HID, DHEAD);
  conv_w<<<WEL / 256, 256, 0, stream>>>(Wv, WvT, 1, HID, SEQ);

  // QH = q @ Wq' (+bq), scatter to [n][b][s][d]
  gemm_bt<<<dim3(64, 8, 1), 256, 0, stream>>>(qbf, WqT, bq, QHb,
                                              8192, 1024, 1024, 0, 0, 0, 0, 0);
  gemm_bt<<<dim3(64, 8, 1), 256, 0, stream>>>(kbf, WkT, bk, KHb,
                                              8192, 1024, 1024, 0, 0, 0, 0, 0);
  // vvT[b][v][t] = WvT (1024x1024) x v^T, bias bv[row]
  gemm_bt<<<dim3(8, 64, 1), 256, 0, stream>>>(WvT, vbf, bv, vvT,
                                              1024, 8192, 1024, 0, 0, 0, 1, 0);

  attn_stats<<<dim3(16, 8, 16), 256, 0, stream>>>(QHb, KHb, m_ws, rl_ws);
  attn_pbar<<<dim3(8, 16, 8), 256, 0, stream>>>(QHb, KHb, m_ws, rl_ws, pbar);

  // out[b] = pbar[b] @ vv[b]  (A=pbar, Bt=vvT), fp32 out, causal K-limit
  gemm_bt<<<dim3(8, 8, 8), 256, 0, stream>>>(pbar, vvT, nullptr, out,
                                             1024, 1024, 1024,
                                             1048576, 1048576, 1048576, 2, 1);
}

// Round 3
// 323.046 us; speedup vs baseline: 1.3176x; 1.0341x over previous
//
#include <hip/hip_runtime.h>

// InterpretableMultiHeadAttention: B=8,S=1024,H=1024,NH=16,D=64,V=1024
// out = (mean_n softmax(causal(qh_n kh_n^T / 8))) @ (v Wv + bv)
// Round 3: stats = per-thread online (m,l) (no in-loop shuffles), K-step 128,
// double-buffered prefetch staging in stats and pbar (1 barrier per step).

#define NHEAD 16
#define BATCH 8
#define SEQ   1024
#define HID   1024
#define DHEAD 64

typedef _Float16 f16;
typedef _Float16 f16x4 __attribute__((ext_vector_type(4)));
typedef _Float16 f16x8 __attribute__((ext_vector_type(8)));
typedef float    f32x4 __attribute__((ext_vector_type(4)));

__device__ __forceinline__ f32x4 mfma16(f16x8 a, f16x8 b, f32x4 c) {
  return __builtin_amdgcn_mfma_f32_16x16x32_f16(a, b, c, 0, 0, 0);
}

__device__ __forceinline__ void gload16(const f16* g, f16* l) {
  __builtin_amdgcn_global_load_lds(
      (const __attribute__((address_space(1))) void*)g,
      (__attribute__((address_space(3))) void*)l, 16, 0, 0);
}

// Stage nch 16B-chunks of a [rows][64]-f16 tile from g (row stride ldg f16)
// into lds. LDS layout linear; global SOURCE chunk pre-swizzled (c16^(row&7))
// so swizzled reads are conflict-free (verified: SQ_LDS_BANK_CONFLICT == 0).
__device__ __forceinline__ void stage_swz(const f16* __restrict__ g, int ldg,
                                          f16* lds, int nch, int tid) {
  for (int idx = tid; idx < nch; idx += 256) {
    int row = idx >> 3, c16 = idx & 7;
    int sc = c16 ^ (row & 7);
    gload16(g + (size_t)row * ldg + sc * 8, lds + (size_t)(idx & ~63) * 8);
  }
}

// Read one f16x8 fragment at (row, 16B-chunk c16) with the matching XOR.
__device__ __forceinline__ f16x8 lds_frag(const f16* lds, int row, int c16) {
  int sc = c16 ^ (row & 7);
  return *(const f16x8*)&lds[row * 64 + sc * 8];
}

// ---------------- conversions ----------------

__global__ __launch_bounds__(256) void conv_f16(const float* __restrict__ src,
                                                f16* __restrict__ dst, int n) {
  int i = (blockIdx.x * 256 + threadIdx.x) * 4;
  if (i >= n) return;
  float4 f = *(const float4*)(src + i);
  f16x4 o = { (f16)f.x, (f16)f.y, (f16)f.z, (f16)f.w };
  *(f16x4*)(dst + i) = o;
}

// in[n][h][d] -> out[n][d][h]  (Wv: n=1, h=1024, d=V=1024)
__global__ __launch_bounds__(256) void conv_w(const float* __restrict__ src,
                                              f16* __restrict__ dst,
                                              int NHp, int Hp, int Dp) {
  int idx = blockIdx.x * 256 + threadIdx.x;
  int total = NHp * Hp * Dp;
  if (idx >= total) return;
  int d = idx % Dp;
  int h = (idx / Dp) % Hp;
  int nn = idx / (Dp * Hp);
  dst[((size_t)nn * Dp + d) * Hp + h] = (f16)src[idx];
}

// ---------------- GEMM: C[m][j] = sum_k A[m][k] * Bt[j][k] (+bias) ----------------
// 128x128 tile, BK=64, 4 waves (2x2), each wave 64x64 via 4x4 16x16 frags.
// epi 0: QH/KH scatter; epi 1: vvT; epi 2: fp32 out batched.
// causal=1: Kend = min(K, row0+128)  (A is lower-triangular pbar)

__global__ __launch_bounds__(256) void gemm_bt(
    const f16* __restrict__ A, const f16* __restrict__ Bt,
    const float* __restrict__ bias, void* __restrict__ C,
    int M, int N, int K, long sAb, long sBb, long sCb, int epi, int causal) {
  A  += (size_t)blockIdx.z * sAb;
  Bt += (size_t)blockIdx.z * sBb;

  __shared__ alignas(16) f16 la[128 * 64];
  __shared__ alignas(16) f16 lb[128 * 64];

  const int tid = threadIdx.x;
  const int lane = tid & 63;
  const int wave = tid >> 6;
  const int wr = wave >> 1, wc = wave & 1;
  const int row0 = blockIdx.x * 128, col0 = blockIdx.y * 128;
  const int Kend = causal ? ((row0 + 128 < K) ? row0 + 128 : K) : K;

  f32x4 acc[4][4];
#pragma unroll
  for (int i = 0; i < 4; i++)
#pragma unroll
    for (int j = 0; j < 4; j++) acc[i][j] = (f32x4){0.f, 0.f, 0.f, 0.f};

  for (int k0 = 0; k0 < Kend; k0 += 64) {
    __syncthreads();  // protect previous iteration's LDS reads
    stage_swz(A + (size_t)row0 * K + k0, K, la, 1024, tid);
    stage_swz(Bt + (size_t)col0 * K + k0, K, lb, 1024, tid);
    __syncthreads();  // barrier drains vmcnt -> loads landed
#pragma unroll
    for (int ks = 0; ks < 2; ks++) {
      f16x8 af[4], bfr[4];
#pragma unroll
      for (int mi = 0; mi < 4; mi++)
        af[mi] = lds_frag(la, wr * 64 + mi * 16 + (lane & 15), ks * 4 + (lane >> 4));
#pragma unroll
      for (int ni = 0; ni < 4; ni++)
        bfr[ni] = lds_frag(lb, wc * 64 + ni * 16 + (lane & 15), ks * 4 + (lane >> 4));
#pragma unroll
      for (int mi = 0; mi < 4; mi++)
#pragma unroll
        for (int ni = 0; ni < 4; ni++)
          acc[mi][ni] = mfma16(af[mi], bfr[ni], acc[mi][ni]);
    }
  }

#pragma unroll
  for (int mi = 0; mi < 4; mi++) {
#pragma unroll
    for (int ni = 0; ni < 4; ni++) {
#pragma unroll
      for (int r = 0; r < 4; r++) {
        int m = row0 + wr * 64 + mi * 16 + ((lane >> 4) << 2) + r;
        int j = col0 + wc * 64 + ni * 16 + (lane & 15);
        float val = acc[mi][ni][r];
        if (epi == 0) {
          val += bias[j];
          int bb = m >> 10, s = m & 1023, hn = j >> 6, d = j & 63;
          ((f16*)C)[(((size_t)hn * BATCH + bb) * SEQ + s) * DHEAD + d] = (f16)val;
        } else if (epi == 1) {
          val += bias[m];
          int bb = j >> 10, t = j & 1023;
          ((f16*)C)[((size_t)bb * SEQ + m) * SEQ + t] = (f16)val;
        } else {
          ((float*)C)[(size_t)blockIdx.z * sCb + (size_t)m * N + j] = val;
        }
      }
    }
  }
}

// ---------------- attention pass 1: per-row max (m) and 1/sum (rl), exp2 domain ----------------
// grid (sb=16, b=8, n=16), block 256 (4 waves x 16 rows).
// Per-thread online (m,l) over own column slice; single 16-lane merge at end.
// K staged in 128-row double-buffered chunks, prefetch before compute.

template <int NTC>
__device__ __forceinline__ void stats_chunk(
    const f16* lkbuf, f16x8 aq0, f16x8 aq1, int lane, int k0, int srow,
    bool masked, float sl2e, float* m_p, float* l_p) {
  f32x4 sc[NTC];
#pragma unroll
  for (int tc = 0; tc < NTC; tc++) {
    f16x8 b0 = lds_frag(lkbuf, tc * 16 + (lane & 15), (lane >> 4));
    f16x8 b1 = lds_frag(lkbuf, tc * 16 + (lane & 15), 4 + (lane >> 4));
    f32x4 c = (f32x4){0.f, 0.f, 0.f, 0.f};
    c = mfma16(aq0, b0, c);
    c = mfma16(aq1, b1, c);
    sc[tc] = c;
  }
#pragma unroll
  for (int r = 0; r < 4; r++) {
    int sg = srow + r;
    float e[NTC];
#pragma unroll
    for (int tc = 0; tc < NTC; tc++) {
      e[tc] = sc[tc][r] * sl2e;
      if (masked) {
        int tg = k0 + tc * 16 + (lane & 15);
        e[tc] = (tg <= sg) ? e[tc] : -1e30f;
      }
    }
    float emax = e[0];
#pragma unroll
    for (int tc = 1; tc < NTC; tc++) emax = fmaxf(emax, e[tc]);
    float mnew = fmaxf(m_p[r], emax);
    float alpha = exp2f(m_p[r] - mnew);  // m_p==-1e30 path: exp2(0)=1, garbage flushed later
    float s = 0.f;
#pragma unroll
    for (int tc = 0; tc < NTC; tc++) s += exp2f(e[tc] - mnew);
    l_p[r] = l_p[r] * alpha + s;
    m_p[r] = mnew;
  }
}

__global__ __launch_bounds__(256) void attn_stats(
    const f16* __restrict__ QH, const f16* __restrict__ KH,
    float* __restrict__ m_ws, float* __restrict__ rl_ws) {
  const int sb = blockIdx.x, b = blockIdx.y, n = blockIdx.z;
  const int s0 = sb * 64;
  const f16* qh = QH + ((size_t)n * BATCH + b) * SEQ * DHEAD;
  const f16* kh = KH + ((size_t)n * BATCH + b) * SEQ * DHEAD;

  __shared__ alignas(16) f16 lq[64 * 64];
  __shared__ alignas(16) f16 lk[2][128 * 64];

  const int tid = threadIdx.x, lane = tid & 63, wave = tid >> 6;
  const int KROWS = (sb + 1) * 64;
  const int nsteps = (KROWS + 127) >> 7;

  stage_swz(qh + (size_t)s0 * 64, 64, lq, 512, tid);
  {
    int rows0 = KROWS < 128 ? KROWS : 128;
    stage_swz(kh, 64, lk[0], rows0 * 8, tid);
  }
  __syncthreads();

  f16x8 aq0 = lds_frag(lq, wave * 16 + (lane & 15), (lane >> 4));
  f16x8 aq1 = lds_frag(lq, wave * 16 + (lane & 15), 4 + (lane >> 4));

  const float sl2e = 0.125f * 1.44269504088896f;  // scale * log2(e)
  float m_p[4] = {-1e30f, -1e30f, -1e30f, -1e30f};
  float l_p[4] = {0.f, 0.f, 0.f, 0.f};
  const int srow = s0 + wave * 16 + ((lane >> 4) << 2);

  int cur = 0;
  for (int st = 0; st < nsteps; st++) {
    int k0 = st << 7;
    int rows = KROWS - k0; if (rows > 128) rows = 128;
    if (st + 1 < nsteps) {
      int k1 = k0 + 128;
      int rows1 = KROWS - k1; if (rows1 > 128) rows1 = 128;
      stage_swz(kh + (size_t)k1 * 64, 64, lk[cur ^ 1], rows1 * 8, tid);
    }
    bool last = (st == nsteps - 1);
    if (rows == 128)
      stats_chunk<8>(lk[cur], aq0, aq1, lane, k0, srow, last, sl2e, m_p, l_p);
    else
      stats_chunk<4>(lk[cur], aq0, aq1, lane, k0, srow, last, sl2e, m_p, l_p);
    __syncthreads();  // reads of cur done; prefetched loads drained
    cur ^= 1;
  }

  // single cross-lane (m,l) merge within each 16-lane group
#pragma unroll
  for (int r = 0; r < 4; r++) {
    float m = m_p[r], l = l_p[r];
#pragma unroll
    for (int off = 1; off < 16; off <<= 1) {
      float m2 = __shfl_xor(m, off);
      float l2 = __shfl_xor(l, off);
      float mn = fmaxf(m, m2);
      l = l * exp2f(m - mn) + l2 * exp2f(m2 - mn);
      m = mn;
    }
    if ((lane & 15) == 0) {
      size_t base = ((size_t)n * BATCH + b) * SEQ;
      m_ws[base + srow + r] = m;
      rl_ws[base + srow + r] = 1.0f / l;
    }
  }
}

// ---------------- attention pass 2: pbar = mean_n p_n, f16, register accumulation ----------------
// grid (tchunk=8, sb=16, b=8), block 256. Heads looped with double-buffered
// prefetch staging (one barrier per head). Fully-masked tiles early-return.

__global__ __launch_bounds__(256) void attn_pbar(
    const f16* __restrict__ QH, const f16* __restrict__ KH,
    const float* __restrict__ m_ws, const float* __restrict__ rl_ws,
    f16* __restrict__ pbar) {
  const int t0 = blockIdx.x * 128;
  const int s0 = blockIdx.y * 64;
  const int b = blockIdx.z;
  if (t0 > s0 + 63) return;  // fully masked; PV never reads this region

  __shared__ alignas(16) f16 lq[2][64 * 64];
  __shared__ alignas(16) f16 lk[2][128 * 64];

  const int tid = threadIdx.x, lane = tid & 63, wave = tid >> 6;
  const float sl2e = 0.125f * 1.44269504088896f;
  const int rloc = wave * 16 + ((lane >> 4) << 2);
  const int srow = s0 + rloc;
  const bool needmask = (t0 + 127 > s0);

  float pacc[8][4];
#pragma unroll
  for (int tc = 0; tc < 8; tc++)
#pragma unroll
    for (int r = 0; r < 4; r++) pacc[tc][r] = 0.f;

  stage_swz(QH + ((size_t)0 * BATCH + b) * SEQ * DHEAD + (size_t)s0 * 64, 64,
            lq[0], 512, tid);
  stage_swz(KH + ((size_t)0 * BATCH + b) * SEQ * DHEAD + (size_t)t0 * 64, 64,
            lk[0], 1024, tid);
  __syncthreads();

  int cur = 0;
  for (int n = 0; n < NHEAD; n++) {
    if (n + 1 < NHEAD) {
      const f16* qh1 = QH + ((size_t)(n + 1) * BATCH + b) * SEQ * DHEAD;
      const f16* kh1 = KH + ((size_t)(n + 1) * BATCH + b) * SEQ * DHEAD;
      stage_swz(qh1 + (size_t)s0 * 64, 64, lq[cur ^ 1], 512, tid);
      stage_swz(kh1 + (size_t)t0 * 64, 64, lk[cur ^ 1], 1024, tid);
    }

    f16x8 aq0 = lds_frag(lq[cur], wave * 16 + (lane & 15), (lane >> 4));
    f16x8 aq1 = lds_frag(lq[cur], wave * 16 + (lane & 15), 4 + (lane >> 4));

    size_t mlbase = ((size_t)n * BATCH + b) * SEQ + srow;
    float4 mr = *(const float4*)&m_ws[mlbase];
    float4 rl = *(const float4*)&rl_ws[mlbase];
    float mrow[4] = {mr.x, mr.y, mr.z, mr.w};
    float rlr[4] = {rl.x * (1.f / 16.f), rl.y * (1.f / 16.f),
                    rl.z * (1.f / 16.f), rl.w * (1.f / 16.f)};

#pragma unroll
    for (int tc = 0; tc < 8; tc++) {
      f16x8 b0 = lds_frag(lk[cur], tc * 16 + (lane & 15), (lane >> 4));
      f16x8 b1 = lds_frag(lk[cur], tc * 16 + (lane & 15), 4 + (lane >> 4));
      f32x4 c = (f32x4){0.f, 0.f, 0.f, 0.f};
      c = mfma16(aq0, b0, c);
      c = mfma16(aq1, b1, c);
      int tg = t0 + tc * 16 + (lane & 15);
#pragma unroll
      for (int r = 0; r < 4; r++) {
        float p = exp2f(fmaf(c[r], sl2e, -mrow[r])) * rlr[r];
        if (needmask) p = (tg <= srow + r) ? p : 0.f;
        pacc[tc][r] += p;
      }
    }
    __syncthreads();  // reads of cur done; prefetched head drained
    cur ^= 1;
  }

#pragma unroll
  for (int tc = 0; tc < 8; tc++) {
    int tg = t0 + tc * 16 + (lane & 15);
#pragma unroll
    for (int r = 0; r < 4; r++)
      pbar[((size_t)b * SEQ + srow + r) * SEQ + tg] = (f16)pacc[tc][r];
  }
}

// ---------------- launcher ----------------

extern "C" void kernel_launch(void* const* d_in, const int* in_sizes, int n_in,
                              void* d_out, int out_size, void* d_ws, size_t ws_size,
                              hipStream_t stream) {
  (void)in_sizes; (void)n_in; (void)out_size; (void)ws_size;
  const float* q  = (const float*)d_in[0];
  const float* k  = (const float*)d_in[1];
  const float* v  = (const float*)d_in[2];
  const float* Wq = (const float*)d_in[3];
  const float* bq = (const float*)d_in[4];
  const float* Wk = (const float*)d_in[5];
  const float* bk = (const float*)d_in[6];
  const float* Wv = (const float*)d_in[7];
  const float* bv = (const float*)d_in[8];
  float* out = (float*)d_out;

  const size_t EL  = (size_t)BATCH * SEQ * HID;      // 8388608
  const size_t WEL = (size_t)NHEAD * HID * DHEAD;    // 1048576

  char* ws = (char*)d_ws;
  f16* qbf = (f16*)ws;  ws += EL * 2;
  f16* kbf = (f16*)ws;  ws += EL * 2;
  f16* vbf = (f16*)ws;  ws += EL * 2;
  f16* WqT = (f16*)ws;  ws += WEL * 2;
  f16* WkT = (f16*)ws;  ws += WEL * 2;
  f16* WvT = (f16*)ws;  ws += WEL * 2;
  f16* QHb = (f16*)ws;  ws += EL * 2;   // [n][b][s][d]
  f16* KHb = (f16*)ws;  ws += EL * 2;   // [n][b][t][d]
  f16* vvT = (f16*)ws;  ws += EL * 2;   // [b][v][t]
  float* m_ws  = (float*)ws; ws += (size_t)NHEAD * BATCH * SEQ * 4;
  float* rl_ws = (float*)ws; ws += (size_t)NHEAD * BATCH * SEQ * 4;
  f16* pbar = (f16*)ws; ws += EL * 2;   // [b][s][t]

  conv_f16<<<EL / 4 / 256, 256, 0, stream>>>(q, qbf, (int)EL);
  conv_f16<<<EL / 4 / 256, 256, 0, stream>>>(k, kbf, (int)EL);
  conv_f16<<<EL / 4 / 256, 256, 0, stream>>>(v, vbf, (int)EL);
  conv_w<<<WEL / 256, 256, 0, stream>>>(Wq, WqT, NHEAD, HID, DHEAD);
  conv_w<<<WEL / 256, 256, 0, stream>>>(Wk, WkT, NHEAD, HID, DHEAD);
  conv_w<<<WEL / 256, 256, 0, stream>>>(Wv, WvT, 1, HID, SEQ);

  // QH = q @ Wq' (+bq), scatter to [n][b][s][d]
  gemm_bt<<<dim3(64, 8, 1), 256, 0, stream>>>(qbf, WqT, bq, QHb,
                                              8192, 1024, 1024, 0, 0, 0, 0, 0);
  gemm_bt<<<dim3(64, 8, 1), 256, 0, stream>>>(kbf, WkT, bk, KHb,
                                              8192, 1024, 1024, 0, 0, 0, 0, 0);
  // vvT[b][v][t] = WvT (1024x1024) x v^T, bias bv[row]
  gemm_bt<<<dim3(8, 64, 1), 256, 0, stream>>>(WvT, vbf, bv, vvT,
                                              1024, 8192, 1024, 0, 0, 0, 1, 0);

  attn_stats<<<dim3(16, 8, 16), 256, 0, stream>>>(QHb, KHb, m_ws, rl_ws);
  attn_pbar<<<dim3(8, 16, 8), 256, 0, stream>>>(QHb, KHb, m_ws, rl_ws, pbar);

  // out[b] = pbar[b] @ vv[b]  (A=pbar, Bt=vvT), fp32 out, causal K-limit
  gemm_bt<<<dim3(8, 8, 8), 256, 0, stream>>>(pbar, vvT, nullptr, out,
                                             1024, 1024, 1024,
                                             1048576, 1048576, 1048576, 2, 1);
}

// Round 5
// 287.894 us; speedup vs baseline: 1.4785x; 1.1221x over previous
//
#include <hip/hip_runtime.h>

// InterpretableMultiHeadAttention: B=8,S=1024,H=1024,NH=16,D=64,V=1024
// out = (mean_n softmax(causal(qh_n kh_n^T / 8))) @ (v Wv + bv)
// Round 5: round-4 structure with pbar_combine coverage bug fixed
// (f16x8 = 8 elements; stride was 16 -> half of pbar never written).

#define NHEAD 16
#define BATCH 8
#define SEQ   1024
#define HID   1024
#define DHEAD 64

typedef _Float16 f16;
typedef _Float16 f16x4 __attribute__((ext_vector_type(4)));
typedef _Float16 f16x8 __attribute__((ext_vector_type(8)));
typedef float    f32x4 __attribute__((ext_vector_type(4)));

__device__ __forceinline__ f32x4 mfma16(f16x8 a, f16x8 b, f32x4 c) {
  return __builtin_amdgcn_mfma_f32_16x16x32_f16(a, b, c, 0, 0, 0);
}

__device__ __forceinline__ void gload16(const f16* g, f16* l) {
  __builtin_amdgcn_global_load_lds(
      (const __attribute__((address_space(1))) void*)g,
      (__attribute__((address_space(3))) void*)l, 16, 0, 0);
}

// Stage nch 16B-chunks of a [rows][64]-f16 tile from g (row stride ldg f16)
// into lds. LDS linear; global SOURCE chunk pre-swizzled (c16^(row&7)) so
// swizzled reads are conflict-free (verified: SQ_LDS_BANK_CONFLICT == 0).
__device__ __forceinline__ void stage_swz(const f16* __restrict__ g, int ldg,
                                          f16* lds, int nch, int tid) {
  for (int idx = tid; idx < nch; idx += 256) {
    int row = idx >> 3, c16 = idx & 7;
    int sc = c16 ^ (row & 7);
    gload16(g + (size_t)row * ldg + sc * 8, lds + (size_t)(idx & ~63) * 8);
  }
}

__device__ __forceinline__ f16x8 lds_frag(const f16* lds, int row, int c16) {
  int sc = c16 ^ (row & 7);
  return *(const f16x8*)&lds[row * 64 + sc * 8];
}

// ---------------- conversions ----------------

__global__ __launch_bounds__(256) void conv_f16(const float* __restrict__ src,
                                                f16* __restrict__ dst, int n) {
  int i = (blockIdx.x * 256 + threadIdx.x) * 4;
  if (i >= n) return;
  float4 f = *(const float4*)(src + i);
  f16x4 o = { (f16)f.x, (f16)f.y, (f16)f.z, (f16)f.w };
  *(f16x4*)(dst + i) = o;
}

// Tiled transpose-convert: src[batch][R][C] f32 -> dst[batch][C][R] f16.
// 64x64 tiles, coalesced float4 loads and f16x8 stores.
__global__ __launch_bounds__(256) void tconv(const float* __restrict__ src,
                                             f16* __restrict__ dst,
                                             int R, int C) {
  const int c0 = blockIdx.x * 64, r0 = blockIdx.y * 64;
  src += (size_t)blockIdx.z * R * C;
  dst += (size_t)blockIdx.z * R * C;
  __shared__ f16 t[64][72];  // +8 pad
  const int tid = threadIdx.x;
#pragma unroll
  for (int i = 0; i < 4; i++) {
    int chunk = tid + i * 256;      // 0..1023
    int row = chunk >> 4, c4 = chunk & 15;
    float4 f = *(const float4*)&src[(size_t)(r0 + row) * C + c0 + c4 * 4];
    f16x4 h = { (f16)f.x, (f16)f.y, (f16)f.z, (f16)f.w };
    *(f16x4*)&t[row][c4 * 4] = h;
  }
  __syncthreads();
  const int cc = tid >> 2, q = tid & 3;
  f16 tmp[16];
#pragma unroll
  for (int j = 0; j < 16; j++) tmp[j] = t[q * 16 + j][cc];
  *(f16x8*)&dst[(size_t)(c0 + cc) * R + r0 + q * 16] = *(f16x8*)&tmp[0];
  *(f16x8*)&dst[(size_t)(c0 + cc) * R + r0 + q * 16 + 8] = *(f16x8*)&tmp[8];
}

// ---------------- GEMM: C[m][j] = sum_k A[m][k] * Bt[j][k] (+bias) ----------------
// 128x128 tile, BK=64, 4 waves (2x2), each wave 64x64 via 4x4 16x16 frags.
// EPI 0: QH/KH scatter; EPI 1: vvT; EPI 2: fp32 out batched.
// CAUSAL: Kend = min(K, row0+128)  (A is lower-triangular pbar)

template <int EPI, int CAUSAL>
__global__ __launch_bounds__(256) void gemm_bt(
    const f16* __restrict__ A, const f16* __restrict__ Bt,
    const float* __restrict__ bias, void* __restrict__ C,
    int M, int N, int K, long sAb, long sBb, long sCb) {
  A  += (size_t)blockIdx.z * sAb;
  Bt += (size_t)blockIdx.z * sBb;

  __shared__ alignas(16) f16 la[128 * 64];
  __shared__ alignas(16) f16 lb[128 * 64];

  const int tid = threadIdx.x;
  const int lane = tid & 63;
  const int wave = tid >> 6;
  const int wr = wave >> 1, wc = wave & 1;
  const int row0 = blockIdx.x * 128, col0 = blockIdx.y * 128;
  const int Kend = CAUSAL ? ((row0 + 128 < K) ? row0 + 128 : K) : K;

  f32x4 acc[4][4];
#pragma unroll
  for (int i = 0; i < 4; i++)
#pragma unroll
    for (int j = 0; j < 4; j++) acc[i][j] = (f32x4){0.f, 0.f, 0.f, 0.f};

  for (int k0 = 0; k0 < Kend; k0 += 64) {
    __syncthreads();  // protect previous iteration's LDS reads
    stage_swz(A + (size_t)row0 * K + k0, K, la, 1024, tid);
    stage_swz(Bt + (size_t)col0 * K + k0, K, lb, 1024, tid);
    __syncthreads();  // barrier drains vmcnt -> loads landed
#pragma unroll
    for (int ks = 0; ks < 2; ks++) {
      f16x8 af[4], bfr[4];
#pragma unroll
      for (int mi = 0; mi < 4; mi++)
        af[mi] = lds_frag(la, wr * 64 + mi * 16 + (lane & 15), ks * 4 + (lane >> 4));
#pragma unroll
      for (int ni = 0; ni < 4; ni++)
        bfr[ni] = lds_frag(lb, wc * 64 + ni * 16 + (lane & 15), ks * 4 + (lane >> 4));
#pragma unroll
      for (int mi = 0; mi < 4; mi++)
#pragma unroll
        for (int ni = 0; ni < 4; ni++)
          acc[mi][ni] = mfma16(af[mi], bfr[ni], acc[mi][ni]);
    }
  }

#pragma unroll
  for (int mi = 0; mi < 4; mi++) {
#pragma unroll
    for (int ni = 0; ni < 4; ni++) {
#pragma unroll
      for (int r = 0; r < 4; r++) {
        int m = row0 + wr * 64 + mi * 16 + ((lane >> 4) << 2) + r;
        int j = col0 + wc * 64 + ni * 16 + (lane & 15);
        float val = acc[mi][ni][r];
        if (EPI == 0) {
          val += bias[j];
          int bb = m >> 10, s = m & 1023, hn = j >> 6, d = j & 63;
          ((f16*)C)[(((size_t)hn * BATCH + bb) * SEQ + s) * DHEAD + d] = (f16)val;
        } else if (EPI == 1) {
          val += bias[m];
          int bb = j >> 10, t = j & 1023;
          ((f16*)C)[((size_t)bb * SEQ + m) * SEQ + t] = (f16)val;
        } else {
          ((float*)C)[(size_t)blockIdx.z * sCb + (size_t)m * N + j] = val;
        }
      }
    }
  }
}

// ---------------- attention pass 1: fused stat madj = -m - log2(l) - 4 ----------------
// grid (sb=16, b=8, n=16), block 256 (4 waves x 16 rows).
// Per-thread online (m,l); single 16-lane merge at end. p = exp2(fma(c,sl2e,madj)).

template <int NTC>
__device__ __forceinline__ void stats_chunk(
    const f16* lkbuf, f16x8 aq0, f16x8 aq1, int lane, int k0, int srow,
    bool masked, float sl2e, float* m_p, float* l_p) {
  f32x4 sc[NTC];
#pragma unroll
  for (int tc = 0; tc < NTC; tc++) {
    f16x8 b0 = lds_frag(lkbuf, tc * 16 + (lane & 15), (lane >> 4));
    f16x8 b1 = lds_frag(lkbuf, tc * 16 + (lane & 15), 4 + (lane >> 4));
    f32x4 c = (f32x4){0.f, 0.f, 0.f, 0.f};
    c = mfma16(aq0, b0, c);
    c = mfma16(aq1, b1, c);
    sc[tc] = c;
  }
#pragma unroll
  for (int r = 0; r < 4; r++) {
    int sg = srow + r;
    float e[NTC];
#pragma unroll
    for (int tc = 0; tc < NTC; tc++) {
      e[tc] = sc[tc][r] * sl2e;
      if (masked) {
        int tg = k0 + tc * 16 + (lane & 15);
        e[tc] = (tg <= sg) ? e[tc] : -1e30f;
      }
    }
    float emax = e[0];
#pragma unroll
    for (int tc = 1; tc < NTC; tc++) emax = fmaxf(emax, e[tc]);
    float mnew = fmaxf(m_p[r], emax);
    float alpha = exp2f(m_p[r] - mnew);
    float s = 0.f;
#pragma unroll
    for (int tc = 0; tc < NTC; tc++) s += exp2f(e[tc] - mnew);
    l_p[r] = l_p[r] * alpha + s;
    m_p[r] = mnew;
  }
}

__global__ __launch_bounds__(256) void attn_stats(
    const f16* __restrict__ QH, const f16* __restrict__ KH,
    float* __restrict__ madj_ws) {
  const int sb = blockIdx.x, b = blockIdx.y, n = blockIdx.z;
  const int s0 = sb * 64;
  const f16* qh = QH + ((size_t)n * BATCH + b) * SEQ * DHEAD;
  const f16* kh = KH + ((size_t)n * BATCH + b) * SEQ * DHEAD;

  __shared__ alignas(16) f16 lq[64 * 64];
  __shared__ alignas(16) f16 lk[2][128 * 64];

  const int tid = threadIdx.x, lane = tid & 63, wave = tid >> 6;
  const int KROWS = (sb + 1) * 64;
  const int nsteps = (KROWS + 127) >> 7;

  stage_swz(qh + (size_t)s0 * 64, 64, lq, 512, tid);
  {
    int rows0 = KROWS < 128 ? KROWS : 128;
    stage_swz(kh, 64, lk[0], rows0 * 8, tid);
  }
  __syncthreads();

  f16x8 aq0 = lds_frag(lq, wave * 16 + (lane & 15), (lane >> 4));
  f16x8 aq1 = lds_frag(lq, wave * 16 + (lane & 15), 4 + (lane >> 4));

  const float sl2e = 0.125f * 1.44269504088896f;  // scale * log2(e)
  float m_p[4] = {-1e30f, -1e30f, -1e30f, -1e30f};
  float l_p[4] = {0.f, 0.f, 0.f, 0.f};
  const int srow = s0 + wave * 16 + ((lane >> 4) << 2);

  int cur = 0;
  for (int st = 0; st < nsteps; st++) {
    int k0 = st << 7;
    int rows = KROWS - k0; if (rows > 128) rows = 128;
    if (st + 1 < nsteps) {
      int k1 = k0 + 128;
      int rows1 = KROWS - k1; if (rows1 > 128) rows1 = 128;
      stage_swz(kh + (size_t)k1 * 64, 64, lk[cur ^ 1], rows1 * 8, tid);
    }
    bool last = (st == nsteps - 1);
    if (rows == 128)
      stats_chunk<8>(lk[cur], aq0, aq1, lane, k0, srow, last, sl2e, m_p, l_p);
    else
      stats_chunk<4>(lk[cur], aq0, aq1, lane, k0, srow, last, sl2e, m_p, l_p);
    __syncthreads();
    cur ^= 1;
  }

#pragma unroll
  for (int r = 0; r < 4; r++) {
    float m = m_p[r], l = l_p[r];
#pragma unroll
    for (int off = 1; off < 16; off <<= 1) {
      float m2 = __shfl_xor(m, off);
      float l2 = __shfl_xor(l, off);
      float mn = fmaxf(m, m2);
      l = l * exp2f(m - mn) + l2 * exp2f(m2 - mn);
      m = mn;
    }
    if ((lane & 15) == 0) {
      size_t base = ((size_t)n * BATCH + b) * SEQ;
      madj_ws[base + srow + r] = -m - __log2f(l) - 4.0f;  // fold 1/l and /16
    }
  }
}

// ---------------- attention pass 2: pbar partials (2 head-groups) ----------------
// grid (tchunk=8, sb=16, b*2+g), block 256. 8 heads per block, double-buffered
// prefetch, one barrier per head. pp[g][b][s][t] f16.

__global__ __launch_bounds__(256) void attn_pbar_part(
    const f16* __restrict__ QH, const f16* __restrict__ KH,
    const float* __restrict__ madj_ws, f16* __restrict__ pp) {
  const int t0 = blockIdx.x * 128;
  const int s0 = blockIdx.y * 64;
  const int bz = blockIdx.z;
  const int b = bz >> 1, g = bz & 1;
  if (t0 > s0 + 63) return;  // fully masked; PV never reads this region

  __shared__ alignas(16) f16 lq[2][64 * 64];
  __shared__ alignas(16) f16 lk[2][128 * 64];

  const int tid = threadIdx.x, lane = tid & 63, wave = tid >> 6;
  const float sl2e = 0.125f * 1.44269504088896f;
  const int rloc = wave * 16 + ((lane >> 4) << 2);
  const int srow = s0 + rloc;
  const bool needmask = (t0 + 127 > s0);
  const int n0 = g * 8;

  float pacc[8][4];
#pragma unroll
  for (int tc = 0; tc < 8; tc++)
#pragma unroll
    for (int r = 0; r < 4; r++) pacc[tc][r] = 0.f;

  stage_swz(QH + ((size_t)n0 * BATCH + b) * SEQ * DHEAD + (size_t)s0 * 64, 64,
            lq[0], 512, tid);
  stage_swz(KH + ((size_t)n0 * BATCH + b) * SEQ * DHEAD + (size_t)t0 * 64, 64,
            lk[0], 1024, tid);
  __syncthreads();

  int cur = 0;
  for (int nn = 0; nn < 8; nn++) {
    const int n = n0 + nn;
    if (nn + 1 < 8) {
      const f16* qh1 = QH + ((size_t)(n + 1) * BATCH + b) * SEQ * DHEAD;
      const f16* kh1 = KH + ((size_t)(n + 1) * BATCH + b) * SEQ * DHEAD;
      stage_swz(qh1 + (size_t)s0 * 64, 64, lq[cur ^ 1], 512, tid);
      stage_swz(kh1 + (size_t)t0 * 64, 64, lk[cur ^ 1], 1024, tid);
    }

    f16x8 aq0 = lds_frag(lq[cur], wave * 16 + (lane & 15), (lane >> 4));
    f16x8 aq1 = lds_frag(lq[cur], wave * 16 + (lane & 15), 4 + (lane >> 4));

    float4 ma = *(const float4*)&madj_ws[((size_t)n * BATCH + b) * SEQ + srow];
    float madj[4] = {ma.x, ma.y, ma.z, ma.w};

#pragma unroll
    for (int tc = 0; tc < 8; tc++) {
      f16x8 b0 = lds_frag(lk[cur], tc * 16 + (lane & 15), (lane >> 4));
      f16x8 b1 = lds_frag(lk[cur], tc * 16 + (lane & 15), 4 + (lane >> 4));
      f32x4 c = (f32x4){0.f, 0.f, 0.f, 0.f};
      c = mfma16(aq0, b0, c);
      c = mfma16(aq1, b1, c);
      int tg = t0 + tc * 16 + (lane & 15);
#pragma unroll
      for (int r = 0; r < 4; r++) {
        float p = exp2f(fmaf(c[r], sl2e, madj[r]));
        if (needmask) p = (tg <= srow + r) ? p : 0.f;
        pacc[tc][r] += p;
      }
    }
    __syncthreads();
    cur ^= 1;
  }

  f16* out = pp + ((size_t)g * BATCH + b) * SEQ * SEQ;
#pragma unroll
  for (int tc = 0; tc < 8; tc++) {
    int tg = t0 + tc * 16 + (lane & 15);
#pragma unroll
    for (int r = 0; r < 4; r++)
      out[(size_t)(srow + r) * SEQ + tg] = (f16)pacc[tc][r];
  }
}

// ---------------- combine: pbar = pp[0] + pp[1] (active tiles only) ----------------
// 256 threads x 32 contiguous elements (4 x f16x8) = full 64x128 tile.

__global__ __launch_bounds__(256) void pbar_combine(const f16* __restrict__ pp,
                                                    f16* __restrict__ pbar) {
  const int t0 = blockIdx.x * 128, s0 = blockIdx.y * 64, b = blockIdx.z;
  if (t0 > s0 + 63) return;
  const int tid = threadIdx.x;
  const int row = tid >> 2, q = tid & 3;
  const size_t GS = (size_t)BATCH * SEQ * SEQ;
  size_t o0 = ((size_t)b * SEQ + s0 + row) * SEQ + t0 + q * 32;
#pragma unroll
  for (int j = 0; j < 4; j++) {  // 4 x 8 elements = 32 contiguous
    f16x8 a = *(const f16x8*)&pp[o0 + j * 8];
    f16x8 c = *(const f16x8*)&pp[GS + o0 + j * 8];
    f16x8 o;
#pragma unroll
    for (int e = 0; e < 8; e++) o[e] = (f16)((float)a[e] + (float)c[e]);
    *(f16x8*)&pbar[o0 + j * 8] = o;
  }
}

// ---------------- launcher ----------------

extern "C" void kernel_launch(void* const* d_in, const int* in_sizes, int n_in,
                              void* d_out, int out_size, void* d_ws, size_t ws_size,
                              hipStream_t stream) {
  (void)in_sizes; (void)n_in; (void)out_size; (void)ws_size;
  const float* q  = (const float*)d_in[0];
  const float* k  = (const float*)d_in[1];
  const float* v  = (const float*)d_in[2];
  const float* Wq = (const float*)d_in[3];
  const float* bq = (const float*)d_in[4];
  const float* Wk = (const float*)d_in[5];
  const float* bk = (const float*)d_in[6];
  const float* Wv = (const float*)d_in[7];
  const float* bv = (const float*)d_in[8];
  float* out = (float*)d_out;

  const size_t EL  = (size_t)BATCH * SEQ * HID;      // 8388608
  const size_t WEL = (size_t)NHEAD * HID * DHEAD;    // 1048576

  char* ws = (char*)d_ws;
  f16* qbf = (f16*)ws;  ws += EL * 2;
  f16* kbf = (f16*)ws;  ws += EL * 2;
  f16* vbf = (f16*)ws;  ws += EL * 2;
  f16* WqT = (f16*)ws;  ws += WEL * 2;
  f16* WkT = (f16*)ws;  ws += WEL * 2;
  f16* WvT = (f16*)ws;  ws += WEL * 2;
  f16* QHb = (f16*)ws;  ws += EL * 2;   // [n][b][s][d]
  f16* KHb = (f16*)ws;  ws += EL * 2;   // [n][b][t][d]
  f16* vvT = (f16*)ws;  ws += EL * 2;   // [b][v][t]
  float* madj_ws = (float*)ws; ws += (size_t)NHEAD * BATCH * SEQ * 4;
  f16* pbar = (f16*)ws; ws += EL * 2;   // [b][s][t]
  // pp[2][b][s][t] f16 overlays qbf+kbf (dead after the projection GEMMs)
  f16* pp = qbf;

  conv_f16<<<EL / 4 / 256, 256, 0, stream>>>(q, qbf, (int)EL);
  conv_f16<<<EL / 4 / 256, 256, 0, stream>>>(k, kbf, (int)EL);
  conv_f16<<<EL / 4 / 256, 256, 0, stream>>>(v, vbf, (int)EL);
  // Wq/Wk: [16][1024][64] -> [16][64][1024]; Wv: [1024][1024] -> transpose
  tconv<<<dim3(1, 16, 16), 256, 0, stream>>>(Wq, WqT, 1024, 64);
  tconv<<<dim3(1, 16, 16), 256, 0, stream>>>(Wk, WkT, 1024, 64);
  tconv<<<dim3(16, 16, 1), 256, 0, stream>>>(Wv, WvT, 1024, 1024);

  // QH = q @ Wq' (+bq), scatter to [n][b][s][d]
  gemm_bt<0, 0><<<dim3(64, 8, 1), 256, 0, stream>>>(qbf, WqT, bq, QHb,
                                                    8192, 1024, 1024, 0, 0, 0);
  gemm_bt<0, 0><<<dim3(64, 8, 1), 256, 0, stream>>>(kbf, WkT, bk, KHb,
                                                    8192, 1024, 1024, 0, 0, 0);
  // vvT[b][v][t] = WvT (1024x1024) x v^T, bias bv[row]
  gemm_bt<1, 0><<<dim3(8, 64, 1), 256, 0, stream>>>(WvT, vbf, bv, vvT,
                                                    1024, 8192, 1024, 0, 0, 0);

  attn_stats<<<dim3(16, 8, 16), 256, 0, stream>>>(QHb, KHb, madj_ws);
  attn_pbar_part<<<dim3(8, 16, BATCH * 2), 256, 0, stream>>>(QHb, KHb, madj_ws, pp);
  pbar_combine<<<dim3(8, 16, BATCH), 256, 0, stream>>>(pp, pbar);

  // out[b] = pbar[b] @ vv[b]  (A=pbar, Bt=vvT), fp32 out, causal K-limit
  gemm_bt<2, 1><<<dim3(8, 8, 8), 256, 0, stream>>>(pbar, vvT, nullptr, out,
                                                   1024, 1024, 1024,
                                                   1048576, 1048576, 1048576);
}

// Round 6
// 272.525 us; speedup vs baseline: 1.5618x; 1.0564x over previous
//
#include <hip/hip_runtime.h>

// InterpretableMultiHeadAttention: B=8,S=1024,H=1024,NH=16,D=64,V=1024
// out = (mean_n softmax(causal(qh_n kh_n^T / 8))) @ (v Wv + bv)
// Round 6: stats without max (scores provably bounded), K/t-chunks 256,
// active-tile-only pbar grid, PV reads both pp partials (no combine),
// consolidated launches (8 dispatches).

#define NHEAD 16
#define BATCH 8
#define SEQ   1024
#define HID   1024
#define DHEAD 64

typedef _Float16 f16;
typedef _Float16 f16x4 __attribute__((ext_vector_type(4)));
typedef _Float16 f16x8 __attribute__((ext_vector_type(8)));
typedef float    f32x4 __attribute__((ext_vector_type(4)));

__device__ __forceinline__ f32x4 mfma16(f16x8 a, f16x8 b, f32x4 c) {
  return __builtin_amdgcn_mfma_f32_16x16x32_f16(a, b, c, 0, 0, 0);
}

__device__ __forceinline__ void gload16(const f16* g, f16* l) {
  __builtin_amdgcn_global_load_lds(
      (const __attribute__((address_space(1))) void*)g,
      (__attribute__((address_space(3))) void*)l, 16, 0, 0);
}

// Stage nch 16B-chunks of a [rows][64]-f16 tile from g (row stride ldg f16)
// into lds. LDS linear; global SOURCE chunk pre-swizzled (c16^(row&7)) so
// swizzled reads are conflict-free (verified: SQ_LDS_BANK_CONFLICT == 0).
__device__ __forceinline__ void stage_swz(const f16* __restrict__ g, int ldg,
                                          f16* lds, int nch, int tid) {
  for (int idx = tid; idx < nch; idx += 256) {
    int row = idx >> 3, c16 = idx & 7;
    int sc = c16 ^ (row & 7);
    gload16(g + (size_t)row * ldg + sc * 8, lds + (size_t)(idx & ~63) * 8);
  }
}

__device__ __forceinline__ f16x8 lds_frag(const f16* lds, int row, int c16) {
  int sc = c16 ^ (row & 7);
  return *(const f16x8*)&lds[row * 64 + sc * 8];
}

// ---------------- conversions ----------------

// grid (EL/4/256, 1, 3): z selects q/k/v
__global__ __launch_bounds__(256) void conv3(
    const float* __restrict__ q, const float* __restrict__ k,
    const float* __restrict__ v, f16* __restrict__ dq, f16* __restrict__ dk,
    f16* __restrict__ dv) {
  const float* src = blockIdx.z == 0 ? q : blockIdx.z == 1 ? k : v;
  f16* dst = blockIdx.z == 0 ? dq : blockIdx.z == 1 ? dk : dv;
  int i = (blockIdx.x * 256 + threadIdx.x) * 4;
  float4 f = *(const float4*)(src + i);
  f16x4 o = { (f16)f.x, (f16)f.y, (f16)f.z, (f16)f.w };
  *(f16x4*)(dst + i) = o;
}

// Tiled transpose-convert: src[z][R][C] f32 -> dst[z][C][R] f16, two ptr sets.
__global__ __launch_bounds__(256) void tconv2(
    const float* __restrict__ s0, const float* __restrict__ s1,
    f16* __restrict__ d0, f16* __restrict__ d1, int R, int C, int half) {
  int z = blockIdx.z;
  const float* src; f16* dst;
  if (z < half) { src = s0 + (size_t)z * R * C; dst = d0 + (size_t)z * R * C; }
  else { src = s1 + (size_t)(z - half) * R * C; dst = d1 + (size_t)(z - half) * R * C; }
  const int c0 = blockIdx.x * 64, r0 = blockIdx.y * 64;
  __shared__ f16 t[64][72];
  const int tid = threadIdx.x;
#pragma unroll
  for (int i = 0; i < 4; i++) {
    int chunk = tid + i * 256;
    int row = chunk >> 4, c4 = chunk & 15;
    float4 f = *(const float4*)&src[(size_t)(r0 + row) * C + c0 + c4 * 4];
    f16x4 h = { (f16)f.x, (f16)f.y, (f16)f.z, (f16)f.w };
    *(f16x4*)&t[row][c4 * 4] = h;
  }
  __syncthreads();
  const int cc = tid >> 2, q = tid & 3;
  f16 tmp[16];
#pragma unroll
  for (int j = 0; j < 16; j++) tmp[j] = t[q * 16 + j][cc];
  *(f16x8*)&dst[(size_t)(c0 + cc) * R + r0 + q * 16] = *(f16x8*)&tmp[0];
  *(f16x8*)&dst[(size_t)(c0 + cc) * R + r0 + q * 16 + 8] = *(f16x8*)&tmp[8];
}

// ---------------- shared GEMM core: 128x128 tile, BK=64, 4 waves ----------------

__device__ __forceinline__ void gemm_core(
    const f16* __restrict__ A, const f16* __restrict__ Bt, int K, int Kend,
    int row0, int col0, f16* la, f16* lb, int tid, f32x4 (&acc)[4][4]) {
  const int lane = tid & 63;
  const int wr = (tid >> 6) >> 1, wc = (tid >> 6) & 1;
  for (int k0 = 0; k0 < Kend; k0 += 64) {
    __syncthreads();
    stage_swz(A + (size_t)row0 * K + k0, K, la, 1024, tid);
    stage_swz(Bt + (size_t)col0 * K + k0, K, lb, 1024, tid);
    __syncthreads();
#pragma unroll
    for (int ks = 0; ks < 2; ks++) {
      f16x8 af[4], bfr[4];
#pragma unroll
      for (int mi = 0; mi < 4; mi++)
        af[mi] = lds_frag(la, wr * 64 + mi * 16 + (lane & 15), ks * 4 + (lane >> 4));
#pragma unroll
      for (int ni = 0; ni < 4; ni++)
        bfr[ni] = lds_frag(lb, wc * 64 + ni * 16 + (lane & 15), ks * 4 + (lane >> 4));
#pragma unroll
      for (int mi = 0; mi < 4; mi++)
#pragma unroll
        for (int ni = 0; ni < 4; ni++)
          acc[mi][ni] = mfma16(af[mi], bfr[ni], acc[mi][ni]);
    }
  }
}

// ---------------- projection GEMM (q & k batched via z) ----------------
// A [8192][1024] f16, Bt [1024][1024] (WqT/WkT rows = out-col j), epi: scatter
// QH/KH [(j>>6)][m>>10][m&1023][j&63] f16 + bias[j].

__global__ __launch_bounds__(256) void proj_gemm(
    const f16* __restrict__ A0, const f16* __restrict__ A1,
    const f16* __restrict__ Bt0, const f16* __restrict__ Bt1,
    const float* __restrict__ bias0, const float* __restrict__ bias1,
    f16* __restrict__ C0, f16* __restrict__ C1) {
  const int which = blockIdx.z;
  const f16* A = which ? A1 : A0;
  const f16* Bt = which ? Bt1 : Bt0;
  const float* bias = which ? bias1 : bias0;
  f16* C = which ? C1 : C0;
  __shared__ alignas(16) f16 la[128 * 64];
  __shared__ alignas(16) f16 lb[128 * 64];
  const int tid = threadIdx.x, lane = tid & 63;
  const int wr = (tid >> 6) >> 1, wc = (tid >> 6) & 1;
  const int row0 = blockIdx.x * 128, col0 = blockIdx.y * 128;
  f32x4 acc[4][4];
#pragma unroll
  for (int i = 0; i < 4; i++)
#pragma unroll
    for (int j = 0; j < 4; j++) acc[i][j] = (f32x4){0.f, 0.f, 0.f, 0.f};
  gemm_core(A, Bt, HID, HID, row0, col0, la, lb, tid, acc);
#pragma unroll
  for (int mi = 0; mi < 4; mi++)
#pragma unroll
    for (int ni = 0; ni < 4; ni++)
#pragma unroll
      for (int r = 0; r < 4; r++) {
        int m = row0 + wr * 64 + mi * 16 + ((lane >> 4) << 2) + r;
        int j = col0 + wc * 64 + ni * 16 + (lane & 15);
        float val = acc[mi][ni][r] + bias[j];
        int bb = m >> 10, s = m & 1023, hn = j >> 6, d = j & 63;
        C[(((size_t)hn * BATCH + bb) * SEQ + s) * DHEAD + d] = (f16)val;
      }
}

// ---------------- vv GEMM: vvT[b][v][t] = WvT x v^T + bv[row] ----------------

__global__ __launch_bounds__(256) void vv_gemm(
    const f16* __restrict__ A, const f16* __restrict__ Bt,
    const float* __restrict__ bias, f16* __restrict__ C) {
  __shared__ alignas(16) f16 la[128 * 64];
  __shared__ alignas(16) f16 lb[128 * 64];
  const int tid = threadIdx.x, lane = tid & 63;
  const int wr = (tid >> 6) >> 1, wc = (tid >> 6) & 1;
  const int row0 = blockIdx.x * 128, col0 = blockIdx.y * 128;
  f32x4 acc[4][4];
#pragma unroll
  for (int i = 0; i < 4; i++)
#pragma unroll
    for (int j = 0; j < 4; j++) acc[i][j] = (f32x4){0.f, 0.f, 0.f, 0.f};
  gemm_core(A, Bt, HID, HID, row0, col0, la, lb, tid, acc);
#pragma unroll
  for (int mi = 0; mi < 4; mi++)
#pragma unroll
    for (int ni = 0; ni < 4; ni++)
#pragma unroll
      for (int r = 0; r < 4; r++) {
        int m = row0 + wr * 64 + mi * 16 + ((lane >> 4) << 2) + r;
        int j = col0 + wc * 64 + ni * 16 + (lane & 15);
        float val = acc[mi][ni][r] + bias[m];
        int bb = j >> 10, t = j & 1023;
        C[((size_t)bb * SEQ + m) * SEQ + t] = (f16)val;
      }
}

// ---------------- attention pass 1: row-sum only (no max; scores bounded) ----
// madj = -log2(l) - 4.  grid (16 sb reversed, 8 b, 16 n). K-chunk 256, dbuf.

template <int NTC>
__device__ __forceinline__ void stats_chunk(
    const f16* lkbuf, f16x8 aq0, f16x8 aq1, int lane, int k0, int srow,
    bool masked, float sl2e, float (&l_p)[4]) {
#pragma unroll
  for (int tc = 0; tc < NTC; tc++) {
    f16x8 b0 = lds_frag(lkbuf, tc * 16 + (lane & 15), (lane >> 4));
    f16x8 b1 = lds_frag(lkbuf, tc * 16 + (lane & 15), 4 + (lane >> 4));
    f32x4 c = (f32x4){0.f, 0.f, 0.f, 0.f};
    c = mfma16(aq0, b0, c);
    c = mfma16(aq1, b1, c);
    int tg = k0 + tc * 16 + (lane & 15);
#pragma unroll
    for (int r = 0; r < 4; r++) {
      float e = exp2f(c[r] * sl2e);
      if (masked) e = (tg <= srow + r) ? e : 0.f;
      l_p[r] += e;
    }
  }
}

__global__ __launch_bounds__(256) void attn_stats(
    const f16* __restrict__ QH, const f16* __restrict__ KH,
    float* __restrict__ madj_ws) {
  const int sb = 15 - blockIdx.x;  // longest-first
  const int b = blockIdx.y, n = blockIdx.z;
  const int s0 = sb * 64;
  const f16* qh = QH + ((size_t)n * BATCH + b) * SEQ * DHEAD;
  const f16* kh = KH + ((size_t)n * BATCH + b) * SEQ * DHEAD;

  __shared__ alignas(16) f16 lq[64 * 64];
  __shared__ alignas(16) f16 lk[2][256 * 64];

  const int tid = threadIdx.x, lane = tid & 63, wave = tid >> 6;
  const int KROWS = s0 + 64;
  const int nsteps = (sb + 4) >> 2;

  stage_swz(qh + (size_t)s0 * 64, 64, lq, 512, tid);
  {
    int rows0 = KROWS < 256 ? KROWS : 256;
    stage_swz(kh, 64, lk[0], rows0 * 8, tid);
  }
  __syncthreads();

  f16x8 aq0 = lds_frag(lq, wave * 16 + (lane & 15), (lane >> 4));
  f16x8 aq1 = lds_frag(lq, wave * 16 + (lane & 15), 4 + (lane >> 4));

  const float sl2e = 0.125f * 1.44269504088896f;
  float l_p[4] = {0.f, 0.f, 0.f, 0.f};
  const int srow = s0 + wave * 16 + ((lane >> 4) << 2);

  int cur = 0;
  for (int st = 0; st < nsteps; st++) {
    int k0 = st << 8;
    int rows = KROWS - k0; if (rows > 256) rows = 256;
    if (st + 1 < nsteps) {
      int rows1 = KROWS - (k0 + 256); if (rows1 > 256) rows1 = 256;
      stage_swz(kh + (size_t)(k0 + 256) * 64, 64, lk[cur ^ 1], rows1 * 8, tid);
    }
    bool last = (st == nsteps - 1);
    if (rows == 256)      stats_chunk<16>(lk[cur], aq0, aq1, lane, k0, srow, last, sl2e, l_p);
    else if (rows == 192) stats_chunk<12>(lk[cur], aq0, aq1, lane, k0, srow, last, sl2e, l_p);
    else if (rows == 128) stats_chunk<8>(lk[cur], aq0, aq1, lane, k0, srow, last, sl2e, l_p);
    else                  stats_chunk<4>(lk[cur], aq0, aq1, lane, k0, srow, last, sl2e, l_p);
    __syncthreads();
    cur ^= 1;
  }

#pragma unroll
  for (int r = 0; r < 4; r++) {
    float l = l_p[r];
#pragma unroll
    for (int off = 1; off < 16; off <<= 1) l += __shfl_xor(l, off);
    if ((lane & 15) == 0) {
      size_t base = ((size_t)n * BATCH + b) * SEQ;
      madj_ws[base + srow + r] = -__log2f(l) - 4.0f;  // folds 1/l and /16
    }
  }
}

// ---------------- attention pass 2: pbar partials, t-chunk 256, active grid --
// grid (40 flat active (sb,tc), 16 = b*2+g). 8 heads/block, dbuf, 1 barrier/head.

__global__ __launch_bounds__(256) void attn_pbar(
    const f16* __restrict__ QH, const f16* __restrict__ KH,
    const float* __restrict__ madj_ws, f16* __restrict__ pp) {
  int f = blockIdx.x, sb = 0, tcid = 0;
  for (int s = 15; s >= 0; --s) {       // longest-first decode
    int c = (s >> 2) + 1;
    if (f < c) { sb = s; tcid = f; break; }
    f -= c;
  }
  const int s0 = sb * 64, t0 = tcid * 256;
  const int b = blockIdx.y >> 1, g = blockIdx.y & 1;

  __shared__ alignas(16) f16 lq[2][64 * 64];
  __shared__ alignas(16) f16 lk[2][256 * 64];

  const int tid = threadIdx.x, lane = tid & 63, wave = tid >> 6;
  const float sl2e = 0.125f * 1.44269504088896f;
  const int srow = s0 + wave * 16 + ((lane >> 4) << 2);
  const int n0 = g * 8;
  const int ntc_act = ((s0 + 63 - t0) >> 4) + 1 < 16 ? ((s0 + 63 - t0) >> 4) + 1 : 16;

  float pacc[16][4];
#pragma unroll
  for (int tc = 0; tc < 16; tc++)
#pragma unroll
    for (int r = 0; r < 4; r++) pacc[tc][r] = 0.f;

  stage_swz(QH + ((size_t)n0 * BATCH + b) * SEQ * DHEAD + (size_t)s0 * 64, 64,
            lq[0], 512, tid);
  stage_swz(KH + ((size_t)n0 * BATCH + b) * SEQ * DHEAD + (size_t)t0 * 64, 64,
            lk[0], 2048, tid);
  __syncthreads();

  int cur = 0;
  for (int nn = 0; nn < 8; nn++) {
    const int n = n0 + nn;
    if (nn + 1 < 8) {
      const f16* qh1 = QH + ((size_t)(n + 1) * BATCH + b) * SEQ * DHEAD;
      const f16* kh1 = KH + ((size_t)(n + 1) * BATCH + b) * SEQ * DHEAD;
      stage_swz(qh1 + (size_t)s0 * 64, 64, lq[cur ^ 1], 512, tid);
      stage_swz(kh1 + (size_t)t0 * 64, 64, lk[cur ^ 1], 2048, tid);
    }

    f16x8 aq0 = lds_frag(lq[cur], wave * 16 + (lane & 15), (lane >> 4));
    f16x8 aq1 = lds_frag(lq[cur], wave * 16 + (lane & 15), 4 + (lane >> 4));

    float4 ma = *(const float4*)&madj_ws[((size_t)n * BATCH + b) * SEQ + srow];
    float madj[4] = {ma.x, ma.y, ma.z, ma.w};

#pragma unroll
    for (int tc = 0; tc < 16; tc++) {
      if (tc < ntc_act) {
        f16x8 b0 = lds_frag(lk[cur], tc * 16 + (lane & 15), (lane >> 4));
        f16x8 b1 = lds_frag(lk[cur], tc * 16 + (lane & 15), 4 + (lane >> 4));
        f32x4 c = (f32x4){0.f, 0.f, 0.f, 0.f};
        c = mfma16(aq0, b0, c);
        c = mfma16(aq1, b1, c);
        int tg = t0 + tc * 16 + (lane & 15);
        bool edge = (t0 + tc * 16 + 15) > s0;
#pragma unroll
        for (int r = 0; r < 4; r++) {
          float p = exp2f(fmaf(c[r], sl2e, madj[r]));
          if (edge) p = (tg <= srow + r) ? p : 0.f;
          pacc[tc][r] += p;
        }
      }
    }
    __syncthreads();
    cur ^= 1;
  }

  f16* out = pp + ((size_t)g * BATCH + b) * SEQ * SEQ;
#pragma unroll
  for (int tc = 0; tc < 16; tc++) {
    int tg = t0 + tc * 16 + (lane & 15);
#pragma unroll
    for (int r = 0; r < 4; r++)
      out[(size_t)(srow + r) * SEQ + tg] = (f16)pacc[tc][r];
  }
}

// ---------------- PV: out[b] = (pp0[b] + pp1[b]) @ vv[b], causal K-limit ----

__global__ __launch_bounds__(256) void pv_gemm(
    const f16* __restrict__ pp, const f16* __restrict__ vvT,
    float* __restrict__ out) {
  const int b = blockIdx.z;
  const size_t GS = (size_t)BATCH * SEQ * SEQ;
  const f16* A0 = pp + (size_t)b * SEQ * SEQ;
  const f16* A1 = pp + GS + (size_t)b * SEQ * SEQ;
  const f16* Bt = vvT + (size_t)b * SEQ * SEQ;
  __shared__ alignas(16) f16 la0[128 * 64];
  __shared__ alignas(16) f16 la1[128 * 64];
  __shared__ alignas(16) f16 lb[128 * 64];
  const int tid = threadIdx.x, lane = tid & 63;
  const int wr = (tid >> 6) >> 1, wc = (tid >> 6) & 1;
  const int row0 = blockIdx.x * 128, col0 = blockIdx.y * 128;
  const int Kend = (row0 + 128 < SEQ) ? row0 + 128 : SEQ;

  f32x4 acc[4][4];
#pragma unroll
  for (int i = 0; i < 4; i++)
#pragma unroll
    for (int j = 0; j < 4; j++) acc[i][j] = (f32x4){0.f, 0.f, 0.f, 0.f};

  for (int k0 = 0; k0 < Kend; k0 += 64) {
    __syncthreads();
    stage_swz(A0 + (size_t)row0 * SEQ + k0, SEQ, la0, 1024, tid);
    stage_swz(A1 + (size_t)row0 * SEQ + k0, SEQ, la1, 1024, tid);
    stage_swz(Bt + (size_t)col0 * SEQ + k0, SEQ, lb, 1024, tid);
    __syncthreads();
#pragma unroll
    for (int ks = 0; ks < 2; ks++) {
      f16x8 a0[4], a1[4], bfr[4];
#pragma unroll
      for (int mi = 0; mi < 4; mi++) {
        a0[mi] = lds_frag(la0, wr * 64 + mi * 16 + (lane & 15), ks * 4 + (lane >> 4));
        a1[mi] = lds_frag(la1, wr * 64 + mi * 16 + (lane & 15), ks * 4 + (lane >> 4));
      }
#pragma unroll
      for (int ni = 0; ni < 4; ni++)
        bfr[ni] = lds_frag(lb, wc * 64 + ni * 16 + (lane & 15), ks * 4 + (lane >> 4));
#pragma unroll
      for (int mi = 0; mi < 4; mi++)
#pragma unroll
        for (int ni = 0; ni < 4; ni++) {
          acc[mi][ni] = mfma16(a0[mi], bfr[ni], acc[mi][ni]);
          acc[mi][ni] = mfma16(a1[mi], bfr[ni], acc[mi][ni]);
        }
    }
  }

#pragma unroll
  for (int mi = 0; mi < 4; mi++)
#pragma unroll
    for (int ni = 0; ni < 4; ni++)
#pragma unroll
      for (int r = 0; r < 4; r++) {
        int m = row0 + wr * 64 + mi * 16 + ((lane >> 4) << 2) + r;
        int j = col0 + wc * 64 + ni * 16 + (lane & 15);
        out[(size_t)b * SEQ * SEQ + (size_t)m * SEQ + j] = acc[mi][ni][r];
      }
}

// ---------------- launcher ----------------

extern "C" void kernel_launch(void* const* d_in, const int* in_sizes, int n_in,
                              void* d_out, int out_size, void* d_ws, size_t ws_size,
                              hipStream_t stream) {
  (void)in_sizes; (void)n_in; (void)out_size; (void)ws_size;
  const float* q  = (const float*)d_in[0];
  const float* k  = (const float*)d_in[1];
  const float* v  = (const float*)d_in[2];
  const float* Wq = (const float*)d_in[3];
  const float* bq = (const float*)d_in[4];
  const float* Wk = (const float*)d_in[5];
  const float* bk = (const float*)d_in[6];
  const float* Wv = (const float*)d_in[7];
  const float* bv = (const float*)d_in[8];
  float* out = (float*)d_out;

  const size_t EL  = (size_t)BATCH * SEQ * HID;      // 8388608
  const size_t WEL = (size_t)NHEAD * HID * DHEAD;    // 1048576

  char* ws = (char*)d_ws;
  f16* qbf = (f16*)ws;  ws += EL * 2;
  f16* kbf = (f16*)ws;  ws += EL * 2;
  f16* vbf = (f16*)ws;  ws += EL * 2;
  f16* WqT = (f16*)ws;  ws += WEL * 2;
  f16* WkT = (f16*)ws;  ws += WEL * 2;
  f16* WvT = (f16*)ws;  ws += WEL * 2;
  f16* QHb = (f16*)ws;  ws += EL * 2;   // [n][b][s][d]
  f16* KHb = (f16*)ws;  ws += EL * 2;   // [n][b][t][d]
  f16* vvT = (f16*)ws;  ws += EL * 2;   // [b][v][t]
  float* madj_ws = (float*)ws; ws += (size_t)NHEAD * BATCH * SEQ * 4;
  // pp[2][b][s][t] f16 overlays qbf+kbf (dead after proj GEMMs)
  f16* pp = qbf;

  conv3<<<dim3(8192, 1, 3), 256, 0, stream>>>(q, k, v, qbf, kbf, vbf);
  tconv2<<<dim3(1, 16, 32), 256, 0, stream>>>(Wq, Wk, WqT, WkT, 1024, 64, 16);
  tconv2<<<dim3(16, 16, 1), 256, 0, stream>>>(Wv, Wv, WvT, WvT, 1024, 1024, 1);

  proj_gemm<<<dim3(64, 8, 2), 256, 0, stream>>>(qbf, kbf, WqT, WkT, bq, bk,
                                                QHb, KHb);
  vv_gemm<<<dim3(8, 64, 1), 256, 0, stream>>>(WvT, vbf, bv, vvT);

  attn_stats<<<dim3(16, 8, 16), 256, 0, stream>>>(QHb, KHb, madj_ws);
  attn_pbar<<<dim3(40, 16, 1), 256, 0, stream>>>(QHb, KHb, madj_ws, pp);
  pv_gemm<<<dim3(8, 8, 8), 256, 0, stream>>>(pp, vvT, out);
}